// Round 1
// baseline (1099.402 us; speedup 1.0000x reference)
//
#include <hip/hip_runtime.h>
#include <hip/hip_bf16.h>

#define N_NODES 50000
#define N_EDGES 500000
#define N_FEAT 128
#define EMB_DIM 1024
#define HIDDEN 128
#define OUT_DIM 10
#define N_GRAPHS 64

// ---------------- init: deg=1 (self loop), zero pool buffers ----------------
__global__ __launch_bounds__(256) void k_init(float* __restrict__ deg,
                                              float* __restrict__ sums,
                                              float* __restrict__ counts) {
    int i = blockIdx.x * 256 + threadIdx.x;
    if (i < N_NODES) deg[i] = 1.0f;
    if (i < N_GRAPHS * HIDDEN) sums[i] = 0.0f;
    if (i < N_GRAPHS) counts[i] = 0.0f;
}

// ---------------- degree scatter ----------------
__global__ __launch_bounds__(256) void k_deg(const int* __restrict__ dst,
                                             const float* __restrict__ ew,
                                             float* __restrict__ deg) {
    int e = blockIdx.x * 256 + threadIdx.x;
    if (e < N_EDGES) atomicAdd(&deg[dst[e]], ew[e]);
}

// ---------------- deg -> dinv (in place) ----------------
__global__ __launch_bounds__(256) void k_dinv(float* __restrict__ deg) {
    int i = blockIdx.x * 256 + threadIdx.x;
    if (i < N_NODES) deg[i] = 1.0f / sqrtf(deg[i]);  // deg >= 1 always (self loop)
}

// ---------------- tiled fp32 GEMM: out[M,128] = A[M,K] @ W[K,128] ----------------
// MODE 0: A row m = [ x[m,0:128] | emb[ids[m], 0:1024] ]  (K=1152)
// MODE 1: A row m = relu(X[m, 0:K])                        (K=128)
template <int MODE>
__global__ __launch_bounds__(256) void k_gemm(const float* __restrict__ X,
                                              const float* __restrict__ EMB,
                                              const int* __restrict__ ids,
                                              const float* __restrict__ W,
                                              float* __restrict__ out, int K) {
    __shared__ float As[16][64];   // transposed A tile: As[k][m]
    __shared__ float Bs[16][128];

    const int tid = threadIdx.x;
    const int tx = tid & 15;       // 0..15 -> col group (8 cols)
    const int ty = tid >> 4;       // 0..15 -> row group (4 rows)
    const int mBase = blockIdx.x * 64;

    // A-load assignment: thread -> (row, 4 contiguous k)
    const int aRow = tid >> 2;           // 0..63
    const int aQ = (tid & 3) * 4;        // 0,4,8,12
    int m = mBase + aRow;
    const int mc = (m < N_NODES) ? m : 0;  // clamp for safe loads
    int embRow = 0;
    if (MODE == 0) embRow = ids[mc];

    // B-load assignment
    const int bRow = tid >> 4;           // 0..15
    const int bCol = (tid & 15) * 8;     // 0..120

    float acc[4][8] = {};

    for (int k0 = 0; k0 < K; k0 += 16) {
        // ---- stage A (gather / relu on the fly) ----
        const float* aptr;
        if (MODE == 0) {
            if (k0 < N_FEAT)
                aptr = X + (size_t)mc * N_FEAT + k0;
            else
                aptr = EMB + (size_t)embRow * EMB_DIM + (k0 - N_FEAT);
        } else {
            aptr = X + (size_t)mc * HIDDEN + k0;
        }
        float4 av = *(const float4*)(aptr + aQ);
        if (MODE == 1) {
            av.x = fmaxf(av.x, 0.f); av.y = fmaxf(av.y, 0.f);
            av.z = fmaxf(av.z, 0.f); av.w = fmaxf(av.w, 0.f);
        }
        As[aQ + 0][aRow] = av.x;
        As[aQ + 1][aRow] = av.y;
        As[aQ + 2][aRow] = av.z;
        As[aQ + 3][aRow] = av.w;

        // ---- stage B ----
        const float* wptr = W + (size_t)(k0 + bRow) * HIDDEN + bCol;
        float4 b0 = *(const float4*)(wptr);
        float4 b1 = *(const float4*)(wptr + 4);
        *(float4*)&Bs[bRow][bCol] = b0;
        *(float4*)&Bs[bRow][bCol + 4] = b1;

        __syncthreads();

#pragma unroll
        for (int kk = 0; kk < 16; kk++) {
            float a[4], b[8];
#pragma unroll
            for (int i = 0; i < 4; i++) a[i] = As[kk][ty * 4 + i];
#pragma unroll
            for (int j = 0; j < 8; j++) b[j] = Bs[kk][tx * 8 + j];
#pragma unroll
            for (int i = 0; i < 4; i++)
#pragma unroll
                for (int j = 0; j < 8; j++) acc[i][j] = fmaf(a[i], b[j], acc[i][j]);
        }
        __syncthreads();
    }

#pragma unroll
    for (int i = 0; i < 4; i++) {
        int row = mBase + ty * 4 + i;
        if (row < N_NODES) {
            float4 v0 = {acc[i][0], acc[i][1], acc[i][2], acc[i][3]};
            float4 v1 = {acc[i][4], acc[i][5], acc[i][6], acc[i][7]};
            *(float4*)(out + (size_t)row * HIDDEN + tx * 8) = v0;
            *(float4*)(out + (size_t)row * HIDDEN + tx * 8 + 4) = v1;
        }
    }
}

// ---------------- aggregation init: out[n,:] = dinv[n]^2 * t[n,:] + b ----------------
__global__ __launch_bounds__(256) void k_agg_init(const float* __restrict__ t,
                                                  const float* __restrict__ dinv,
                                                  const float* __restrict__ b,
                                                  float* __restrict__ out) {
    int idx = blockIdx.x * 256 + threadIdx.x;  // float4 index
    const int total = N_NODES * HIDDEN / 4;
    if (idx >= total) return;
    int n = idx / (HIDDEN / 4);
    int f4 = idx % (HIDDEN / 4);
    float d = dinv[n];
    float s = d * d;
    float4 tv = ((const float4*)t)[idx];
    float4 bv = ((const float4*)b)[f4];
    float4 o = {fmaf(s, tv.x, bv.x), fmaf(s, tv.y, bv.y),
                fmaf(s, tv.z, bv.z), fmaf(s, tv.w, bv.w)};
    ((float4*)out)[idx] = o;
}

// ---------------- edge scatter: out[dst,:] += norm * t[src,:] ----------------
__global__ __launch_bounds__(256) void k_agg_edges(const int* __restrict__ src,
                                                   const int* __restrict__ dst,
                                                   const float* __restrict__ ew,
                                                   const float* __restrict__ dinv,
                                                   const float* __restrict__ t,
                                                   float* __restrict__ out) {
    int e = blockIdx.x * 2 + (threadIdx.x >> 7);
    int f = threadIdx.x & 127;
    if (e >= N_EDGES) return;
    int s = src[e];
    int d = dst[e];
    float norm = dinv[s] * ew[e] * dinv[d];
    atomicAdd(&out[(size_t)d * HIDDEN + f], norm * t[(size_t)s * HIDDEN + f]);
}

// ---------------- pool: per-graph sums of relu(out2), batch sorted ----------------
__global__ __launch_bounds__(128) void k_pool(const float* __restrict__ h,
                                              const int* __restrict__ batch,
                                              float* __restrict__ sums,
                                              float* __restrict__ counts) {
    const int CHUNK = 256;
    int n0 = blockIdx.x * CHUNK;
    int f = threadIdx.x;
    float acc = 0.f, cnt = 0.f;
    int cur = -1;
    for (int i = 0; i < CHUNK; i++) {
        int n = n0 + i;
        if (n >= N_NODES) break;
        int g = batch[n];
        if (g != cur) {
            if (cur >= 0) {
                atomicAdd(&sums[cur * HIDDEN + f], acc);
                if (f == 0) atomicAdd(&counts[cur], cnt);
            }
            cur = g;
            acc = 0.f;
            cnt = 0.f;
        }
        acc += fmaxf(h[(size_t)n * HIDDEN + f], 0.f);
        cnt += 1.f;
    }
    if (cur >= 0) {
        atomicAdd(&sums[cur * HIDDEN + f], acc);
        if (f == 0) atomicAdd(&counts[cur], cnt);
    }
}

// ---------------- final: out[g,o] = (sums[g,:] @ fcW[:,o]) / max(cnt,1) + fcb[o] ----
__global__ __launch_bounds__(64) void k_final(const float* __restrict__ sums,
                                              const float* __restrict__ counts,
                                              const float* __restrict__ fcW,
                                              const float* __restrict__ fcb,
                                              float* __restrict__ out) {
    int g = blockIdx.x;
    int o = threadIdx.x;
    if (o >= OUT_DIM) return;
    float inv = 1.0f / fmaxf(counts[g], 1.0f);
    float acc = 0.f;
    for (int f = 0; f < HIDDEN; f++)
        acc = fmaf(sums[g * HIDDEN + f], fcW[f * OUT_DIM + o], acc);
    out[g * OUT_DIM + o] = acc * inv + fcb[o];
}

extern "C" void kernel_launch(void* const* d_in, const int* in_sizes, int n_in,
                              void* d_out, int out_size, void* d_ws, size_t ws_size,
                              hipStream_t stream) {
    const float* x      = (const float*)d_in[0];
    const float* ew     = (const float*)d_in[1];
    const float* emb    = (const float*)d_in[2];
    const float* W1     = (const float*)d_in[3];
    const float* b1     = (const float*)d_in[4];
    const float* W2     = (const float*)d_in[5];
    const float* b2     = (const float*)d_in[6];
    const float* fcW    = (const float*)d_in[7];
    const float* fcb    = (const float*)d_in[8];
    const int* edge_idx = (const int*)d_in[9];
    const int* batch    = (const int*)d_in[10];
    const int* node_ids = (const int*)d_in[11];
    float* out = (float*)d_out;

    const int* src = edge_idx;             // edge_index[0]
    const int* dst = edge_idx + N_EDGES;   // edge_index[1]

    // workspace layout (floats, 64-float aligned)
    float* ws = (float*)d_ws;
    float* dinv   = ws;                     // 50000 (deg then dinv in place)
    float* bufA   = ws + 50048;             // 6.4M   (t1, later t2)
    float* bufB   = bufA + 6400000;         // 6.4M   (out1, later out2)
    float* sums   = bufB + 6400000;         // 8192
    float* counts = sums + N_GRAPHS * HIDDEN;  // 64

    const int NB_NODE = (N_NODES + 255) / 256;       // 196
    const int NB_EDGE = (N_EDGES + 255) / 256;       // 1954
    const int NB_GEMM = (N_NODES + 63) / 64;         // 782
    const int NB_AGGI = (N_NODES * HIDDEN / 4 + 255) / 256;  // 6250
    const int NB_SCAT = N_EDGES / 2;                 // 250000
    const int NB_POOL = (N_NODES + 255) / 256;       // 196

    // degree / normalization (shared by both convs)
    k_init<<<NB_NODE, 256, 0, stream>>>(dinv, sums, counts);
    k_deg<<<NB_EDGE, 256, 0, stream>>>(dst, ew, dinv);
    k_dinv<<<NB_NODE, 256, 0, stream>>>(dinv);

    // conv1: t1 = [x|emb[ids]] @ W1 ; out1 = aggregate + b1
    k_gemm<0><<<NB_GEMM, 256, 0, stream>>>(x, emb, node_ids, W1, bufA, N_FEAT + EMB_DIM);
    k_agg_init<<<NB_AGGI, 256, 0, stream>>>(bufA, dinv, b1, bufB);
    k_agg_edges<<<NB_SCAT, 256, 0, stream>>>(src, dst, ew, dinv, bufA, bufB);

    // conv2: t2 = relu(out1) @ W2 ; out2 = aggregate + b2
    k_gemm<1><<<NB_GEMM, 256, 0, stream>>>(bufB, nullptr, nullptr, W2, bufA, HIDDEN);
    k_agg_init<<<NB_AGGI, 256, 0, stream>>>(bufA, dinv, b2, bufB);
    k_agg_edges<<<NB_SCAT, 256, 0, stream>>>(src, dst, ew, dinv, bufA, bufB);

    // pool (relu fused) + classifier
    k_pool<<<NB_POOL, 128, 0, stream>>>(bufB, batch, sums, counts);
    k_final<<<N_GRAPHS, 64, 0, stream>>>(sums, counts, fcW, fcb, out);
}

// Round 2
// 896.910 us; speedup vs baseline: 1.2258x; 1.2258x over previous
//
#include <hip/hip_runtime.h>
#include <hip/hip_bf16.h>

#define N_NODES 50000
#define N_EDGES 500000
#define N_FEAT 128
#define EMB_DIM 1024
#define HIDDEN 128
#define OUT_DIM 10
#define N_GRAPHS 64
#define SCAN_T 1024

// ---- async global->LDS, 16B per lane; LDS dst must be wave-uniform base ----
__device__ __forceinline__ void load_lds16(const float* g, float* l) {
    __builtin_amdgcn_global_load_lds(
        (const __attribute__((address_space(1))) unsigned int*)g,
        (__attribute__((address_space(3))) unsigned int*)l, 16, 0, 0);
}

// ---------------- init: deg=1 (self loop), cnt=0, zero pool buffers ----------------
__global__ __launch_bounds__(256) void k_init(float* __restrict__ deg,
                                              int* __restrict__ cnt,
                                              float* __restrict__ sums,
                                              float* __restrict__ counts) {
    int i = blockIdx.x * 256 + threadIdx.x;
    if (i < N_NODES) { deg[i] = 1.0f; cnt[i] = 0; }
    if (i < N_GRAPHS * HIDDEN) sums[i] = 0.0f;
    if (i < N_GRAPHS) counts[i] = 0.0f;
}

// ---------------- degree scatter: weighted deg (float) + in-degree count (int) ------
__global__ __launch_bounds__(256) void k_deg(const int* __restrict__ dst,
                                             const float* __restrict__ ew,
                                             float* __restrict__ deg,
                                             int* __restrict__ cnt) {
    int e = blockIdx.x * 256 + threadIdx.x;
    if (e < N_EDGES) {
        int d = dst[e];
        atomicAdd(&deg[d], ew[e]);
        atomicAdd(&cnt[d], 1);
    }
}

// ---------------- deg -> dinv (in place) ----------------
__global__ __launch_bounds__(256) void k_dinv(float* __restrict__ deg) {
    int i = blockIdx.x * 256 + threadIdx.x;
    if (i < N_NODES) deg[i] = 1.0f / sqrtf(deg[i]);  // deg >= 1 (self loop)
}

// ---------------- single-block exclusive scan: cnt -> rowptr, cnt becomes cursor ----
__global__ __launch_bounds__(SCAN_T) void k_scan(int* __restrict__ cntcur,
                                                 int* __restrict__ rowptr) {
    __shared__ int part[SCAN_T];
    const int t = threadIdx.x;
    const int CH = (N_NODES + SCAN_T - 1) / SCAN_T;  // 49
    const int lo = t * CH;
    const int hi = (lo + CH < N_NODES) ? lo + CH : N_NODES;
    int s = 0;
    for (int i = lo; i < hi; i++) s += cntcur[i];
    part[t] = s;
    __syncthreads();
    for (int off = 1; off < SCAN_T; off <<= 1) {
        int v = (t >= off) ? part[t - off] : 0;
        __syncthreads();
        part[t] += v;
        __syncthreads();
    }
    int base = part[t] - s;  // exclusive prefix
    for (int i = lo; i < hi; i++) {
        int c = cntcur[i];      // read BEFORE overwriting (cursor aliases cnt)
        rowptr[i] = base;
        cntcur[i] = base;       // cursor start
        base += c;
    }
    if (t == SCAN_T - 1) rowptr[N_NODES] = base;  // == N_EDGES
}

// ---------------- fill CSR: csr[pos] = (src, norm) ----------------
__global__ __launch_bounds__(256) void k_fill(const int* __restrict__ src,
                                              const int* __restrict__ dst,
                                              const float* __restrict__ ew,
                                              const float* __restrict__ dinv,
                                              int* __restrict__ cursor,
                                              int2* __restrict__ csr) {
    int e = blockIdx.x * 256 + threadIdx.x;
    if (e >= N_EDGES) return;
    int s = src[e], d = dst[e];
    int pos = atomicAdd(&cursor[d], 1);
    float norm = dinv[s] * ew[e] * dinv[d];
    csr[pos] = make_int2(s, __float_as_int(norm));
}

// ---------------- tiled fp32 GEMM: out[M,128] = A[M,K] @ W[K,128] ----------------
// 64x128 tile / 128 threads (2 waves), BK=32, 8x8 per-thread accum.
// MODE 0: A row m = [ x[m,0:128] | emb[ids[m],0:1024] ]  (K=1152)
// MODE 1: A row m = relu(X[m,0:128])                      (K=128)
template <int MODE>
__global__ __launch_bounds__(128) void k_gemm(const float* __restrict__ X,
                                              const float* __restrict__ EMB,
                                              const int* __restrict__ ids,
                                              const float* __restrict__ W,
                                              float* __restrict__ out, int K) {
    __shared__ float As[32][68];   // transposed A tile, stride 68: pad kills conflicts,
                                   // keeps ty*8 reads 16B-aligned
    __shared__ float Bs[32][128];  // row-major W tile (global_load_lds layout)

    const int tid = threadIdx.x;
    const int lane = tid & 63;
    const int wv = tid >> 6;        // wave 0..1
    const int tx = tid & 15;        // col group: cols tx*4 and 64+tx*4
    const int ty = tid >> 4;        // row group: rows ty*8 .. ty*8+7
    const int mBase = blockIdx.x * 64;

    // A staging: thread -> (row = tid>>1, 16 k-contiguous floats at (tid&1)*16)
    const int aRow = tid >> 1;
    const int aQ = (tid & 1) * 16;
    const int m = mBase + aRow;
    const int mc = (m < N_NODES) ? m : (N_NODES - 1);
    int embRow = 0;
    if (MODE == 0) embRow = ids[mc];

    float acc[8][8] = {};

    for (int k0 = 0; k0 < K; k0 += 32) {
        // ---- stage A (gather / relu on the fly), write transposed ----
        const float* aptr;
        if (MODE == 0) {
            aptr = (k0 < N_FEAT) ? (X + (size_t)mc * N_FEAT + k0)
                                 : (EMB + (size_t)embRow * EMB_DIM + (k0 - N_FEAT));
        } else {
            aptr = X + (size_t)mc * HIDDEN + k0;
        }
        float4 a0 = *(const float4*)(aptr + aQ);
        float4 a1 = *(const float4*)(aptr + aQ + 4);
        float4 a2 = *(const float4*)(aptr + aQ + 8);
        float4 a3 = *(const float4*)(aptr + aQ + 12);
        if (MODE == 1) {
            a0.x=fmaxf(a0.x,0.f); a0.y=fmaxf(a0.y,0.f); a0.z=fmaxf(a0.z,0.f); a0.w=fmaxf(a0.w,0.f);
            a1.x=fmaxf(a1.x,0.f); a1.y=fmaxf(a1.y,0.f); a1.z=fmaxf(a1.z,0.f); a1.w=fmaxf(a1.w,0.f);
            a2.x=fmaxf(a2.x,0.f); a2.y=fmaxf(a2.y,0.f); a2.z=fmaxf(a2.z,0.f); a2.w=fmaxf(a2.w,0.f);
            a3.x=fmaxf(a3.x,0.f); a3.y=fmaxf(a3.y,0.f); a3.z=fmaxf(a3.z,0.f); a3.w=fmaxf(a3.w,0.f);
        }
        As[aQ+ 0][aRow]=a0.x; As[aQ+ 1][aRow]=a0.y; As[aQ+ 2][aRow]=a0.z; As[aQ+ 3][aRow]=a0.w;
        As[aQ+ 4][aRow]=a1.x; As[aQ+ 5][aRow]=a1.y; As[aQ+ 6][aRow]=a1.z; As[aQ+ 7][aRow]=a1.w;
        As[aQ+ 8][aRow]=a2.x; As[aQ+ 9][aRow]=a2.y; As[aQ+10][aRow]=a2.z; As[aQ+11][aRow]=a2.w;
        As[aQ+12][aRow]=a3.x; As[aQ+13][aRow]=a3.y; As[aQ+14][aRow]=a3.z; As[aQ+15][aRow]=a3.w;

        // ---- stage B via async global->LDS: wave wv covers rows 16*wv..16*wv+15 ----
        {
            const float* wbase = W + (size_t)(k0 + 16 * wv) * HIDDEN;  // 2 rows per call
#pragma unroll
            for (int c = 0; c < 8; c++)
                load_lds16(wbase + c * 256 + lane * 4, &Bs[16 * wv + 2 * c][0]);
        }
        __syncthreads();

#pragma unroll 4
        for (int kk = 0; kk < 32; kk++) {
            float a[8], b[8];
            *(float4*)&a[0] = *(const float4*)&As[kk][ty * 8];
            *(float4*)&a[4] = *(const float4*)&As[kk][ty * 8 + 4];
            *(float4*)&b[0] = *(const float4*)&Bs[kk][tx * 4];
            *(float4*)&b[4] = *(const float4*)&Bs[kk][64 + tx * 4];
#pragma unroll
            for (int i = 0; i < 8; i++)
#pragma unroll
                for (int j = 0; j < 8; j++) acc[i][j] = fmaf(a[i], b[j], acc[i][j]);
        }
        __syncthreads();
    }

#pragma unroll
    for (int i = 0; i < 8; i++) {
        int row = mBase + ty * 8 + i;
        if (row < N_NODES) {
            float4 v0 = {acc[i][0], acc[i][1], acc[i][2], acc[i][3]};
            float4 v1 = {acc[i][4], acc[i][5], acc[i][6], acc[i][7]};
            *(float4*)(out + (size_t)row * HIDDEN + tx * 4) = v0;
            *(float4*)(out + (size_t)row * HIDDEN + 64 + tx * 4) = v1;
        }
    }
}

// ---------------- CSR gather-aggregate, one wave per node (no atomics) -------------
// out[n,:] = sum_e norm_e * t[src_e,:]  +  dinv[n]^2 * t[n,:]  +  b
__global__ __launch_bounds__(256) void k_agg(const int2* __restrict__ csr,
                                             const int* __restrict__ rowptr,
                                             const float* __restrict__ dinv,
                                             const float* __restrict__ t,
                                             const float* __restrict__ b,
                                             float* __restrict__ out) {
    const int n = (blockIdx.x * 256 + threadIdx.x) >> 6;  // node = global wave id
    const int lane = threadIdx.x & 63;
    if (n >= N_NODES) return;

    const int beg = rowptr[n];
    const int end = rowptr[n + 1];
    const float di = dinv[n];
    const float sc = di * di;

    float2 tv = ((const float2*)(t + (size_t)n * HIDDEN))[lane];
    float2 bv = ((const float2*)b)[lane];
    float2 acc = {fmaf(sc, tv.x, bv.x), fmaf(sc, tv.y, bv.y)};

    int e = beg;
    for (; e + 1 < end; e += 2) {
        int2 c0 = csr[e];
        int2 c1 = csr[e + 1];
        float2 r0 = ((const float2*)(t + (size_t)c0.x * HIDDEN))[lane];
        float2 r1 = ((const float2*)(t + (size_t)c1.x * HIDDEN))[lane];
        float w0 = __int_as_float(c0.y);
        float w1 = __int_as_float(c1.y);
        acc.x = fmaf(w0, r0.x, acc.x); acc.y = fmaf(w0, r0.y, acc.y);
        acc.x = fmaf(w1, r1.x, acc.x); acc.y = fmaf(w1, r1.y, acc.y);
    }
    if (e < end) {
        int2 c0 = csr[e];
        float2 r0 = ((const float2*)(t + (size_t)c0.x * HIDDEN))[lane];
        float w0 = __int_as_float(c0.y);
        acc.x = fmaf(w0, r0.x, acc.x); acc.y = fmaf(w0, r0.y, acc.y);
    }
    ((float2*)(out + (size_t)n * HIDDEN))[lane] = acc;
}

// ---------------- pool: per-graph sums of relu(out2), batch sorted ----------------
__global__ __launch_bounds__(128) void k_pool(const float* __restrict__ h,
                                              const int* __restrict__ batch,
                                              float* __restrict__ sums,
                                              float* __restrict__ counts) {
    const int CHUNK = 256;
    int n0 = blockIdx.x * CHUNK;
    int f = threadIdx.x;
    float acc = 0.f, cnt = 0.f;
    int cur = -1;
    for (int i = 0; i < CHUNK; i++) {
        int n = n0 + i;
        if (n >= N_NODES) break;
        int g = batch[n];
        if (g != cur) {
            if (cur >= 0) {
                atomicAdd(&sums[cur * HIDDEN + f], acc);
                if (f == 0) atomicAdd(&counts[cur], cnt);
            }
            cur = g; acc = 0.f; cnt = 0.f;
        }
        acc += fmaxf(h[(size_t)n * HIDDEN + f], 0.f);
        cnt += 1.f;
    }
    if (cur >= 0) {
        atomicAdd(&sums[cur * HIDDEN + f], acc);
        if (f == 0) atomicAdd(&counts[cur], cnt);
    }
}

// ---------------- final: out[g,o] = (sums[g,:]/max(cnt,1)) @ fcW + fcb -------------
__global__ __launch_bounds__(64) void k_final(const float* __restrict__ sums,
                                              const float* __restrict__ counts,
                                              const float* __restrict__ fcW,
                                              const float* __restrict__ fcb,
                                              float* __restrict__ out) {
    int g = blockIdx.x;
    int o = threadIdx.x;
    if (o >= OUT_DIM) return;
    float inv = 1.0f / fmaxf(counts[g], 1.0f);
    float acc = 0.f;
    for (int f = 0; f < HIDDEN; f++)
        acc = fmaf(sums[g * HIDDEN + f], fcW[f * OUT_DIM + o], acc);
    out[g * OUT_DIM + o] = acc * inv + fcb[o];
}

extern "C" void kernel_launch(void* const* d_in, const int* in_sizes, int n_in,
                              void* d_out, int out_size, void* d_ws, size_t ws_size,
                              hipStream_t stream) {
    const float* x      = (const float*)d_in[0];
    const float* ew     = (const float*)d_in[1];
    const float* emb    = (const float*)d_in[2];
    const float* W1     = (const float*)d_in[3];
    const float* b1     = (const float*)d_in[4];
    const float* W2     = (const float*)d_in[5];
    const float* b2     = (const float*)d_in[6];
    const float* fcW    = (const float*)d_in[7];
    const float* fcb    = (const float*)d_in[8];
    const int* edge_idx = (const int*)d_in[9];
    const int* batch    = (const int*)d_in[10];
    const int* node_ids = (const int*)d_in[11];
    float* out = (float*)d_out;

    const int* src = edge_idx;             // edge_index[0]
    const int* dst = edge_idx + N_EDGES;   // edge_index[1]

    // workspace layout (4B units; csr offset is 8B-aligned)
    float* ws     = (float*)d_ws;
    float* dinv   = ws;                                  // 50048
    int*   cntcur = (int*)(ws + 50048);                  // 50048 (count, then cursor)
    int*   rowptr = (int*)(ws + 100096);                 // 50056
    int2*  csr    = (int2*)(ws + 150152);                // 500000 int2 = 1,000,000
    float* bufA   = ws + 1150152;                        // 6.4M  (t1, then t2)
    float* bufB   = bufA + 6400000;                      // 6.4M  (out1, then out2)
    float* sums   = bufB + 6400000;                      // 8192
    float* counts = sums + N_GRAPHS * HIDDEN;            // 64
    // total ~55.8 MB

    const int NB_NODE = (N_NODES + 255) / 256;           // 196
    const int NB_EDGE = (N_EDGES + 255) / 256;           // 1954
    const int NB_GEMM = (N_NODES + 63) / 64;             // 782
    const int NB_AGG  = (N_NODES + 3) / 4;               // 12500 (4 waves/block)
    const int NB_POOL = (N_NODES + 255) / 256;           // 196

    // graph preprocessing (shared by both convs)
    k_init<<<NB_NODE, 256, 0, stream>>>(dinv, cntcur, sums, counts);
    k_deg <<<NB_EDGE, 256, 0, stream>>>(dst, ew, dinv, cntcur);
    k_dinv<<<NB_NODE, 256, 0, stream>>>(dinv);
    k_scan<<<1, SCAN_T, 0, stream>>>(cntcur, rowptr);
    k_fill<<<NB_EDGE, 256, 0, stream>>>(src, dst, ew, dinv, cntcur, csr);

    // conv1: t1 = [x|emb] @ W1 ; out1 = csr-aggregate + self-loop + b1
    k_gemm<0><<<NB_GEMM, 128, 0, stream>>>(x, emb, node_ids, W1, bufA, N_FEAT + EMB_DIM);
    k_agg<<<NB_AGG, 256, 0, stream>>>(csr, rowptr, dinv, bufA, b1, bufB);

    // conv2: t2 = relu(out1) @ W2 ; out2 = csr-aggregate + self-loop + b2
    k_gemm<1><<<NB_GEMM, 128, 0, stream>>>(bufB, nullptr, nullptr, W2, bufA, HIDDEN);
    k_agg<<<NB_AGG, 256, 0, stream>>>(csr, rowptr, dinv, bufA, b2, bufB);

    // pool (relu fused) + classifier
    k_pool<<<NB_POOL, 128, 0, stream>>>(bufB, batch, sums, counts);
    k_final<<<N_GRAPHS, 64, 0, stream>>>(sums, counts, fcW, fcb, out);
}

// Round 3
// 752.009 us; speedup vs baseline: 1.4620x; 1.1927x over previous
//
#include <hip/hip_runtime.h>
#include <hip/hip_bf16.h>

#define N_NODES 50000
#define N_EDGES 500000
#define N_FEAT 128
#define EMB_DIM 1024
#define HIDDEN 128
#define OUT_DIM 10
#define N_GRAPHS 64
#define SCAN_T 1024

typedef __attribute__((ext_vector_type(8))) short short8;   // 8 bf16 = 4 VGPR (MFMA A/B frag)
typedef __attribute__((ext_vector_type(4))) float f32x4;    // MFMA C/D frag

// ---- fp32 -> bf16 RTN-even (finite inputs), and back ----
__device__ __forceinline__ unsigned short f2bf(float f) {
    unsigned int u = __float_as_uint(f);
    return (unsigned short)((u + 0x7fffu + ((u >> 16) & 1u)) >> 16);
}
__device__ __forceinline__ float bf2f(unsigned short h) {
    return __uint_as_float(((unsigned int)h) << 16);
}

// ---------------- init: deg=1 (self loop), cnt=0, zero pool buffers ----------------
__global__ __launch_bounds__(256) void k_init(float* __restrict__ deg,
                                              int* __restrict__ cnt,
                                              float* __restrict__ sums,
                                              float* __restrict__ counts) {
    int i = blockIdx.x * 256 + threadIdx.x;
    if (i < N_NODES) { deg[i] = 1.0f; cnt[i] = 0; }
    if (i < N_GRAPHS * HIDDEN) sums[i] = 0.0f;
    if (i < N_GRAPHS) counts[i] = 0.0f;
}

// ---------------- degree scatter: weighted deg (float) + in-degree count (int) ------
__global__ __launch_bounds__(256) void k_deg(const int* __restrict__ dst,
                                             const float* __restrict__ ew,
                                             float* __restrict__ deg,
                                             int* __restrict__ cnt) {
    int e = blockIdx.x * 256 + threadIdx.x;
    if (e < N_EDGES) {
        int d = dst[e];
        atomicAdd(&deg[d], ew[e]);
        atomicAdd(&cnt[d], 1);
    }
}

// ---------------- deg -> dinv (in place) ----------------
__global__ __launch_bounds__(256) void k_dinv(float* __restrict__ deg) {
    int i = blockIdx.x * 256 + threadIdx.x;
    if (i < N_NODES) deg[i] = 1.0f / sqrtf(deg[i]);  // deg >= 1 (self loop)
}

// ---------------- single-block exclusive scan: cnt -> rowptr, cnt becomes cursor ----
__global__ __launch_bounds__(SCAN_T) void k_scan(int* __restrict__ cntcur,
                                                 int* __restrict__ rowptr) {
    __shared__ int part[SCAN_T];
    const int t = threadIdx.x;
    const int CH = (N_NODES + SCAN_T - 1) / SCAN_T;  // 49
    const int lo = t * CH;
    const int hi = (lo + CH < N_NODES) ? lo + CH : N_NODES;
    int s = 0;
    for (int i = lo; i < hi; i++) s += cntcur[i];
    part[t] = s;
    __syncthreads();
    for (int off = 1; off < SCAN_T; off <<= 1) {
        int v = (t >= off) ? part[t - off] : 0;
        __syncthreads();
        part[t] += v;
        __syncthreads();
    }
    int base = part[t] - s;  // exclusive prefix
    for (int i = lo; i < hi; i++) {
        int c = cntcur[i];      // read BEFORE overwriting (cursor aliases cnt)
        rowptr[i] = base;
        cntcur[i] = base;       // cursor start
        base += c;
    }
    if (t == SCAN_T - 1) rowptr[N_NODES] = base;  // == N_EDGES
}

// ---------------- fill CSR: csr[pos] = (src, norm) ----------------
__global__ __launch_bounds__(256) void k_fill(const int* __restrict__ src,
                                              const int* __restrict__ dst,
                                              const float* __restrict__ ew,
                                              const float* __restrict__ dinv,
                                              int* __restrict__ cursor,
                                              int2* __restrict__ csr) {
    int e = blockIdx.x * 256 + threadIdx.x;
    if (e >= N_EDGES) return;
    int s = src[e], d = dst[e];
    int pos = atomicAdd(&cursor[d], 1);
    float norm = dinv[s] * ew[e] * dinv[d];
    csr[pos] = make_int2(s, __float_as_int(norm));
}

// ---------------- W (K x 128) -> Wt (128 x K) split to bf16 hi/lo ----------------
// thread t: n = t&127, k-chunk c = t>>7 (16 k per thread). Coalesced reads per k row.
__global__ __launch_bounds__(256) void k_prep(const float* __restrict__ W,
                                              unsigned short* __restrict__ WtH,
                                              unsigned short* __restrict__ WtL,
                                              int K) {
    int t = blockIdx.x * 256 + threadIdx.x;
    int n = t & 127;
    int c = t >> 7;
    if (c * 16 >= K) return;
    unsigned short h[16], l[16];
#pragma unroll
    for (int i = 0; i < 16; i++) {
        float v = W[(size_t)(c * 16 + i) * HIDDEN + n];
        h[i] = f2bf(v);
        l[i] = f2bf(v - bf2f(h[i]));
    }
    short8 h0, h1, l0, l1;
#pragma unroll
    for (int i = 0; i < 8; i++) { h0[i] = (short)h[i]; h1[i] = (short)h[i + 8];
                                  l0[i] = (short)l[i]; l1[i] = (short)l[i + 8]; }
    size_t o = (size_t)n * K + c * 16;
    *(short8*)&WtH[o] = h0; *(short8*)&WtH[o + 8] = h1;
    *(short8*)&WtL[o] = l0; *(short8*)&WtL[o + 8] = l1;
}

// ---------------- split-bf16 MFMA GEMM: out[M,128] = A[M,K] @ W[K,128] (fp32-acc) ---
// Block: 128 M-rows x 128 N-cols, 256 threads (4 waves 2x2), 64x64 per wave.
// 3-MFMA combo per tile: aH*bH + aH*bL + aL*bH  (error ~2^-17 relative).
// MODE 0: A row m = [ x[m,0:128] | emb[ids[m],0:1024] ]  (K=1152)
// MODE 1: A row m = relu(X[m,0:128])                      (K=128)
template <int MODE>
__global__ __launch_bounds__(256) void k_gemm(const float* __restrict__ X,
                                              const float* __restrict__ EMB,
                                              const int* __restrict__ ids,
                                              const unsigned short* __restrict__ WtH,
                                              const unsigned short* __restrict__ WtL,
                                              float* __restrict__ out, int K) {
    __shared__ unsigned short AsH[128][40];  // [row][k], stride 40 (80 B, 16B-aligned)
    __shared__ unsigned short AsL[128][40];
    __shared__ unsigned short BsH[128][40];  // [col][k]
    __shared__ unsigned short BsL[128][40];

    const int tid = threadIdx.x;
    const int lane = tid & 63;
    const int wv = tid >> 6;
    const int wm = wv >> 1, wn = wv & 1;     // wave quadrant
    const int fr = lane & 15;                // frag row/col
    const int fq = lane >> 4;                // frag k-octet
    const int mBase = blockIdx.x * 128;

    // staging map: thread -> (row 0..127, 16 k at (tid&1)*16)
    const int aRow = tid >> 1;
    const int aOff = (tid & 1) * 16;
    const int m = mBase + aRow;
    const int mc = (m < N_NODES) ? m : (N_NODES - 1);
    int embRow = 0;
    if (MODE == 0) embRow = ids[mc];

    f32x4 acc[4][4];
#pragma unroll
    for (int i = 0; i < 4; i++)
#pragma unroll
        for (int j = 0; j < 4; j++) acc[i][j] = (f32x4){0.f, 0.f, 0.f, 0.f};

    // ---- prefetch k0=0 globals into registers ----
    float av[16];
    short8 bh0, bh1, bl0, bl1;
    {
        const float* aptr = (MODE == 0)
            ? X + (size_t)mc * N_FEAT + aOff
            : X + (size_t)mc * HIDDEN + aOff;
        *(float4*)&av[0]  = *(const float4*)(aptr);
        *(float4*)&av[4]  = *(const float4*)(aptr + 4);
        *(float4*)&av[8]  = *(const float4*)(aptr + 8);
        *(float4*)&av[12] = *(const float4*)(aptr + 12);
        size_t bo = (size_t)aRow * K + aOff;
        bh0 = *(const short8*)&WtH[bo]; bh1 = *(const short8*)&WtH[bo + 8];
        bl0 = *(const short8*)&WtL[bo]; bl1 = *(const short8*)&WtL[bo + 8];
    }

    for (int k0 = 0; k0 < K; k0 += 32) {
        // ---- convert A regs to hi/lo and commit staged regs to LDS ----
        short8 ah0, ah1, al0, al1;
#pragma unroll
        for (int i = 0; i < 16; i++) {
            float v = av[i];
            if (MODE == 1) v = fmaxf(v, 0.f);
            unsigned short h = f2bf(v);
            unsigned short l = f2bf(v - bf2f(h));
            if (i < 8) { ah0[i] = (short)h; al0[i] = (short)l; }
            else       { ah1[i - 8] = (short)h; al1[i - 8] = (short)l; }
        }
        *(short8*)&AsH[aRow][aOff] = ah0; *(short8*)&AsH[aRow][aOff + 8] = ah1;
        *(short8*)&AsL[aRow][aOff] = al0; *(short8*)&AsL[aRow][aOff + 8] = al1;
        *(short8*)&BsH[aRow][aOff] = bh0; *(short8*)&BsH[aRow][aOff + 8] = bh1;
        *(short8*)&BsL[aRow][aOff] = bl0; *(short8*)&BsL[aRow][aOff + 8] = bl1;
        __syncthreads();

        // ---- prefetch next k-step globals (latency hidden behind MFMAs) ----
        int k1 = k0 + 32;
        if (k1 < K) {
            const float* aptr;
            if (MODE == 0)
                aptr = (k1 < N_FEAT) ? X + (size_t)mc * N_FEAT + k1 + aOff
                                     : EMB + (size_t)embRow * EMB_DIM + (k1 - N_FEAT) + aOff;
            else
                aptr = X + (size_t)mc * HIDDEN + k1 + aOff;
            *(float4*)&av[0]  = *(const float4*)(aptr);
            *(float4*)&av[4]  = *(const float4*)(aptr + 4);
            *(float4*)&av[8]  = *(const float4*)(aptr + 8);
            *(float4*)&av[12] = *(const float4*)(aptr + 12);
            size_t bo = (size_t)aRow * K + k1 + aOff;
            bh0 = *(const short8*)&WtH[bo]; bh1 = *(const short8*)&WtH[bo + 8];
            bl0 = *(const short8*)&WtL[bo]; bl1 = *(const short8*)&WtL[bo + 8];
        }

        // ---- fragment loads (k 0..31 across lanes: k = fq*8 + j) ----
        short8 aH[4], aL[4], bH[4], bL[4];
#pragma unroll
        for (int i = 0; i < 4; i++) {
            aH[i] = *(const short8*)&AsH[wm * 64 + i * 16 + fr][fq * 8];
            aL[i] = *(const short8*)&AsL[wm * 64 + i * 16 + fr][fq * 8];
            bH[i] = *(const short8*)&BsH[wn * 64 + i * 16 + fr][fq * 8];
            bL[i] = *(const short8*)&BsL[wn * 64 + i * 16 + fr][fq * 8];
        }

        // ---- 48 MFMAs: 3 combos x 16 tiles (16 indep between acc reuses) ----
#pragma unroll
        for (int i = 0; i < 4; i++)
#pragma unroll
            for (int j = 0; j < 4; j++)
                acc[i][j] = __builtin_amdgcn_mfma_f32_16x16x32_bf16(aH[i], bH[j], acc[i][j], 0, 0, 0);
#pragma unroll
        for (int i = 0; i < 4; i++)
#pragma unroll
            for (int j = 0; j < 4; j++)
                acc[i][j] = __builtin_amdgcn_mfma_f32_16x16x32_bf16(aH[i], bL[j], acc[i][j], 0, 0, 0);
#pragma unroll
        for (int i = 0; i < 4; i++)
#pragma unroll
            for (int j = 0; j < 4; j++)
                acc[i][j] = __builtin_amdgcn_mfma_f32_16x16x32_bf16(aL[i], bH[j], acc[i][j], 0, 0, 0);
        __syncthreads();
    }

    // ---- epilogue: C/D map col=lane&15, row=(lane>>4)*4+reg ----
#pragma unroll
    for (int i = 0; i < 4; i++) {
#pragma unroll
        for (int j = 0; j < 4; j++) {
            int gcol = wn * 64 + j * 16 + fr;
#pragma unroll
            for (int r = 0; r < 4; r++) {
                int grow = mBase + wm * 64 + i * 16 + fq * 4 + r;
                if (grow < N_NODES) out[(size_t)grow * HIDDEN + gcol] = acc[i][j][r];
            }
        }
    }
}

// ---------------- CSR gather-aggregate, one wave per node (no atomics) -------------
// out[n,:] = sum_e norm_e * t[src_e,:]  +  dinv[n]^2 * t[n,:]  +  b
__global__ __launch_bounds__(256) void k_agg(const int2* __restrict__ csr,
                                             const int* __restrict__ rowptr,
                                             const float* __restrict__ dinv,
                                             const float* __restrict__ t,
                                             const float* __restrict__ b,
                                             float* __restrict__ out) {
    const int n = (blockIdx.x * 256 + threadIdx.x) >> 6;  // node = global wave id
    const int lane = threadIdx.x & 63;
    if (n >= N_NODES) return;

    const int beg = rowptr[n];
    const int end = rowptr[n + 1];
    const float di = dinv[n];
    const float sc = di * di;

    float2 tv = ((const float2*)(t + (size_t)n * HIDDEN))[lane];
    float2 bv = ((const float2*)b)[lane];
    float2 acc = {fmaf(sc, tv.x, bv.x), fmaf(sc, tv.y, bv.y)};

    int e = beg;
    for (; e + 1 < end; e += 2) {
        int2 c0 = csr[e];
        int2 c1 = csr[e + 1];
        float2 r0 = ((const float2*)(t + (size_t)c0.x * HIDDEN))[lane];
        float2 r1 = ((const float2*)(t + (size_t)c1.x * HIDDEN))[lane];
        float w0 = __int_as_float(c0.y);
        float w1 = __int_as_float(c1.y);
        acc.x = fmaf(w0, r0.x, acc.x); acc.y = fmaf(w0, r0.y, acc.y);
        acc.x = fmaf(w1, r1.x, acc.x); acc.y = fmaf(w1, r1.y, acc.y);
    }
    if (e < end) {
        int2 c0 = csr[e];
        float2 r0 = ((const float2*)(t + (size_t)c0.x * HIDDEN))[lane];
        float w0 = __int_as_float(c0.y);
        acc.x = fmaf(w0, r0.x, acc.x); acc.y = fmaf(w0, r0.y, acc.y);
    }
    ((float2*)(out + (size_t)n * HIDDEN))[lane] = acc;
}

// ---------------- pool: per-graph sums of relu(out2), batch sorted ----------------
__global__ __launch_bounds__(128) void k_pool(const float* __restrict__ h,
                                              const int* __restrict__ batch,
                                              float* __restrict__ sums,
                                              float* __restrict__ counts) {
    const int CHUNK = 256;
    int n0 = blockIdx.x * CHUNK;
    int f = threadIdx.x;
    float acc = 0.f, cnt = 0.f;
    int cur = -1;
    for (int i = 0; i < CHUNK; i++) {
        int n = n0 + i;
        if (n >= N_NODES) break;
        int g = batch[n];
        if (g != cur) {
            if (cur >= 0) {
                atomicAdd(&sums[cur * HIDDEN + f], acc);
                if (f == 0) atomicAdd(&counts[cur], cnt);
            }
            cur = g; acc = 0.f; cnt = 0.f;
        }
        acc += fmaxf(h[(size_t)n * HIDDEN + f], 0.f);
        cnt += 1.f;
    }
    if (cur >= 0) {
        atomicAdd(&sums[cur * HIDDEN + f], acc);
        if (f == 0) atomicAdd(&counts[cur], cnt);
    }
}

// ---------------- final: out[g,o] = (sums[g,:]/max(cnt,1)) @ fcW + fcb -------------
__global__ __launch_bounds__(64) void k_final(const float* __restrict__ sums,
                                              const float* __restrict__ counts,
                                              const float* __restrict__ fcW,
                                              const float* __restrict__ fcb,
                                              float* __restrict__ out) {
    int g = blockIdx.x;
    int o = threadIdx.x;
    if (o >= OUT_DIM) return;
    float inv = 1.0f / fmaxf(counts[g], 1.0f);
    float acc = 0.f;
    for (int f = 0; f < HIDDEN; f++)
        acc = fmaf(sums[g * HIDDEN + f], fcW[f * OUT_DIM + o], acc);
    out[g * OUT_DIM + o] = acc * inv + fcb[o];
}

extern "C" void kernel_launch(void* const* d_in, const int* in_sizes, int n_in,
                              void* d_out, int out_size, void* d_ws, size_t ws_size,
                              hipStream_t stream) {
    const float* x      = (const float*)d_in[0];
    const float* ew     = (const float*)d_in[1];
    const float* emb    = (const float*)d_in[2];
    const float* W1     = (const float*)d_in[3];
    const float* b1     = (const float*)d_in[4];
    const float* W2     = (const float*)d_in[5];
    const float* b2     = (const float*)d_in[6];
    const float* fcW    = (const float*)d_in[7];
    const float* fcb    = (const float*)d_in[8];
    const int* edge_idx = (const int*)d_in[9];
    const int* batch    = (const int*)d_in[10];
    const int* node_ids = (const int*)d_in[11];
    float* out = (float*)d_out;

    const int* src = edge_idx;             // edge_index[0]
    const int* dst = edge_idx + N_EDGES;   // edge_index[1]

    // workspace layout (4B units; csr offset 8B-aligned)
    float* ws     = (float*)d_ws;
    float* dinv   = ws;                                  // 50048
    int*   cntcur = (int*)(ws + 50048);                  // 50048
    int*   rowptr = (int*)(ws + 100096);                 // 50056
    int2*  csr    = (int2*)(ws + 150152);                // 500000 int2
    float* bufA   = ws + 1150152;                        // 6.4M (t1, then t2)
    float* bufB   = bufA + 6400000;                      // 6.4M (out1, then out2)
    float* sums   = bufB + 6400000;                      // 8192
    float* counts = sums + N_GRAPHS * HIDDEN;            // 64
    unsigned short* wtH1 = (unsigned short*)(ws + 13958408);  // 128*1152
    unsigned short* wtL1 = (unsigned short*)(ws + 14032136);
    unsigned short* wtH2 = (unsigned short*)(ws + 14105864);  // 128*128
    unsigned short* wtL2 = (unsigned short*)(ws + 14114056);
    // end ~14122248 floats = 56.5 MB

    const int NB_NODE = (N_NODES + 255) / 256;           // 196
    const int NB_EDGE = (N_EDGES + 255) / 256;           // 1954
    const int NB_GEMM = (N_NODES + 127) / 128;           // 391
    const int NB_AGG  = (N_NODES + 3) / 4;               // 12500
    const int NB_POOL = (N_NODES + 255) / 256;           // 196
    const int K1 = N_FEAT + EMB_DIM;                     // 1152

    // graph preprocessing + weight conversion
    k_init<<<NB_NODE, 256, 0, stream>>>(dinv, cntcur, sums, counts);
    k_deg <<<NB_EDGE, 256, 0, stream>>>(dst, ew, dinv, cntcur);
    k_dinv<<<NB_NODE, 256, 0, stream>>>(dinv);
    k_scan<<<1, SCAN_T, 0, stream>>>(cntcur, rowptr);
    k_fill<<<NB_EDGE, 256, 0, stream>>>(src, dst, ew, dinv, cntcur, csr);
    k_prep<<<K1 / 32, 256, 0, stream>>>(W1, wtH1, wtL1, K1);       // 36 blocks
    k_prep<<<HIDDEN / 32, 256, 0, stream>>>(W2, wtH2, wtL2, HIDDEN);

    // conv1: t1 = [x|emb] @ W1 ; out1 = csr-aggregate + self-loop + b1
    k_gemm<0><<<NB_GEMM, 256, 0, stream>>>(x, emb, node_ids, wtH1, wtL1, bufA, K1);
    k_agg<<<NB_AGG, 256, 0, stream>>>(csr, rowptr, dinv, bufA, b1, bufB);

    // conv2: t2 = relu(out1) @ W2 ; out2 = csr-aggregate + self-loop + b2
    k_gemm<1><<<NB_GEMM, 256, 0, stream>>>(bufB, nullptr, nullptr, wtH2, wtL2, bufA, HIDDEN);
    k_agg<<<NB_AGG, 256, 0, stream>>>(csr, rowptr, dinv, bufA, b2, bufB);

    // pool (relu fused) + classifier
    k_pool<<<NB_POOL, 128, 0, stream>>>(bufB, batch, sums, counts);
    k_final<<<N_GRAPHS, 64, 0, stream>>>(sums, counts, fcW, fcb, out);
}

// Round 4
// 694.570 us; speedup vs baseline: 1.5829x; 1.0827x over previous
//
#include <hip/hip_runtime.h>
#include <hip/hip_bf16.h>

#define N_NODES 50000
#define N_EDGES 500000
#define N_FEAT 128
#define EMB_DIM 1024
#define HIDDEN 128
#define OUT_DIM 10
#define N_GRAPHS 64
#define SCAN_T 1024

typedef __attribute__((ext_vector_type(8))) short short8;   // 8 bf16 = 4 VGPR (MFMA A/B frag)
typedef __attribute__((ext_vector_type(4))) float f32x4;    // MFMA C/D frag

// ---- fp32 -> bf16 RTN-even (finite inputs), and back ----
__device__ __forceinline__ unsigned short f2bf(float f) {
    unsigned int u = __float_as_uint(f);
    return (unsigned short)((u + 0x7fffu + ((u >> 16) & 1u)) >> 16);
}
__device__ __forceinline__ float bf2f(unsigned short h) {
    return __uint_as_float(((unsigned int)h) << 16);
}
// unpack a dword holding 2 bf16 (elements 2k, 2k+1)
__device__ __forceinline__ float bflo(unsigned int r) { return __uint_as_float(r << 16); }
__device__ __forceinline__ float bfhi(unsigned int r) { return __uint_as_float(r & 0xffff0000u); }

// ---------------- init: deg=1 (self loop), cnt=0, zero pool buffers ----------------
__global__ __launch_bounds__(256) void k_init(float* __restrict__ deg,
                                              int* __restrict__ cnt,
                                              float* __restrict__ sums,
                                              float* __restrict__ counts) {
    int i = blockIdx.x * 256 + threadIdx.x;
    if (i < N_NODES) { deg[i] = 1.0f; cnt[i] = 0; }
    if (i < N_GRAPHS * HIDDEN) sums[i] = 0.0f;
    if (i < N_GRAPHS) counts[i] = 0.0f;
}

// ---------------- degree scatter: weighted deg (float) + in-degree count (int) ------
__global__ __launch_bounds__(256) void k_deg(const int* __restrict__ dst,
                                             const float* __restrict__ ew,
                                             float* __restrict__ deg,
                                             int* __restrict__ cnt) {
    int e = blockIdx.x * 256 + threadIdx.x;
    if (e < N_EDGES) {
        int d = dst[e];
        atomicAdd(&deg[d], ew[e]);
        atomicAdd(&cnt[d], 1);
    }
}

// ---------------- scan (cnt -> rowptr, cnt becomes cursor) + dinv in one launch -----
__global__ __launch_bounds__(SCAN_T) void k_scan(int* __restrict__ cntcur,
                                                 int* __restrict__ rowptr,
                                                 float* __restrict__ dinv) {
    __shared__ int part[SCAN_T];
    const int t = threadIdx.x;
    const int CH = (N_NODES + SCAN_T - 1) / SCAN_T;  // 49
    const int lo = t * CH;
    const int hi = (lo + CH < N_NODES) ? lo + CH : N_NODES;
    for (int i = lo; i < hi; i++) dinv[i] = 1.0f / sqrtf(dinv[i]);  // deg >= 1
    int s = 0;
    for (int i = lo; i < hi; i++) s += cntcur[i];
    part[t] = s;
    __syncthreads();
    for (int off = 1; off < SCAN_T; off <<= 1) {
        int v = (t >= off) ? part[t - off] : 0;
        __syncthreads();
        part[t] += v;
        __syncthreads();
    }
    int base = part[t] - s;  // exclusive prefix
    for (int i = lo; i < hi; i++) {
        int c = cntcur[i];      // read BEFORE overwriting (cursor aliases cnt)
        rowptr[i] = base;
        cntcur[i] = base;       // cursor start
        base += c;
    }
    if (t == SCAN_T - 1) rowptr[N_NODES] = base;  // == N_EDGES
}

// ---------------- fill CSR: csr[pos] = (src, norm) ----------------
__global__ __launch_bounds__(256) void k_fill(const int* __restrict__ src,
                                              const int* __restrict__ dst,
                                              const float* __restrict__ ew,
                                              const float* __restrict__ dinv,
                                              int* __restrict__ cursor,
                                              int2* __restrict__ csr) {
    int e = blockIdx.x * 256 + threadIdx.x;
    if (e >= N_EDGES) return;
    int s = src[e], d = dst[e];
    int pos = atomicAdd(&cursor[d], 1);
    float norm = dinv[s] * ew[e] * dinv[d];
    csr[pos] = make_int2(s, __float_as_int(norm));
}

// ---------------- W (K x 128) -> Wt (128 x K) split to bf16 hi/lo (both W1, W2) ----
__device__ __forceinline__ void prep_one(const float* __restrict__ W,
                                         unsigned short* __restrict__ WtH,
                                         unsigned short* __restrict__ WtL,
                                         int K, int t) {
    int n = t & 127;
    int c = t >> 7;
    if (c * 16 >= K) return;
    short8 h0, h1, l0, l1;
#pragma unroll
    for (int i = 0; i < 16; i++) {
        float v = W[(size_t)(c * 16 + i) * HIDDEN + n];
        unsigned short h = f2bf(v);
        unsigned short l = f2bf(v - bf2f(h));
        if (i < 8) { h0[i] = (short)h; l0[i] = (short)l; }
        else       { h1[i - 8] = (short)h; l1[i - 8] = (short)l; }
    }
    size_t o = (size_t)n * K + c * 16;
    *(short8*)&WtH[o] = h0; *(short8*)&WtH[o + 8] = h1;
    *(short8*)&WtL[o] = l0; *(short8*)&WtL[o + 8] = l1;
}

__global__ __launch_bounds__(256) void k_prep(const float* __restrict__ W1,
                                              unsigned short* __restrict__ WtH1,
                                              unsigned short* __restrict__ WtL1,
                                              const float* __restrict__ W2,
                                              unsigned short* __restrict__ WtH2,
                                              unsigned short* __restrict__ WtL2) {
    int b = blockIdx.x;
    if (b < 36) prep_one(W1, WtH1, WtL1, N_FEAT + EMB_DIM, b * 256 + threadIdx.x);
    else        prep_one(W2, WtH2, WtL2, HIDDEN, (b - 36) * 256 + threadIdx.x);
}

// ---------------- split-bf16 MFMA GEMM: tbf[M,128] = A[M,K] @ W[K,128], bf16 out ----
// Block: 128x128, 256 threads (4 waves 2x2), 64x64 per wave, BK=32.
// 3-MFMA combo per tile: aH*bH + aH*bL + aL*bH.
// MODE 0: A row m = [ x[m,0:128] | emb[ids[m],0:1024] ]  (K=1152)
// MODE 1: A row m = relu(X[m,0:128])                      (K=128)
template <int MODE>
__global__ __launch_bounds__(256) void k_gemm(const float* __restrict__ X,
                                              const float* __restrict__ EMB,
                                              const int* __restrict__ ids,
                                              const unsigned short* __restrict__ WtH,
                                              const unsigned short* __restrict__ WtL,
                                              unsigned short* __restrict__ tbf, int K) {
    __shared__ unsigned short AsH[128][40];  // [row][k], stride 40 (80 B, 16B-aligned)
    __shared__ unsigned short AsL[128][40];
    __shared__ unsigned short BsH[128][40];  // [col][k]
    __shared__ unsigned short BsL[128][40];

    const int tid = threadIdx.x;
    const int lane = tid & 63;
    const int wv = tid >> 6;
    const int wm = wv >> 1, wn = wv & 1;     // wave quadrant
    const int fr = lane & 15;                // frag row/col
    const int fq = lane >> 4;                // frag k-octet
    const int mBase = blockIdx.x * 128;

    const int aRow = tid >> 1;
    const int aOff = (tid & 1) * 16;
    const int m = mBase + aRow;
    const int mc = (m < N_NODES) ? m : (N_NODES - 1);
    int embRow = 0;
    if (MODE == 0) embRow = ids[mc];

    f32x4 acc[4][4];
#pragma unroll
    for (int i = 0; i < 4; i++)
#pragma unroll
        for (int j = 0; j < 4; j++) acc[i][j] = (f32x4){0.f, 0.f, 0.f, 0.f};

    // prefetch k0=0 globals
    float av[16];
    short8 bh0, bh1, bl0, bl1;
    {
        const float* aptr = (MODE == 0)
            ? X + (size_t)mc * N_FEAT + aOff
            : X + (size_t)mc * HIDDEN + aOff;
        *(float4*)&av[0]  = *(const float4*)(aptr);
        *(float4*)&av[4]  = *(const float4*)(aptr + 4);
        *(float4*)&av[8]  = *(const float4*)(aptr + 8);
        *(float4*)&av[12] = *(const float4*)(aptr + 12);
        size_t bo = (size_t)aRow * K + aOff;
        bh0 = *(const short8*)&WtH[bo]; bh1 = *(const short8*)&WtH[bo + 8];
        bl0 = *(const short8*)&WtL[bo]; bl1 = *(const short8*)&WtL[bo + 8];
    }

    for (int k0 = 0; k0 < K; k0 += 32) {
        short8 ah0, ah1, al0, al1;
#pragma unroll
        for (int i = 0; i < 16; i++) {
            float v = av[i];
            if (MODE == 1) v = fmaxf(v, 0.f);
            unsigned short h = f2bf(v);
            unsigned short l = f2bf(v - bf2f(h));
            if (i < 8) { ah0[i] = (short)h; al0[i] = (short)l; }
            else       { ah1[i - 8] = (short)h; al1[i - 8] = (short)l; }
        }
        *(short8*)&AsH[aRow][aOff] = ah0; *(short8*)&AsH[aRow][aOff + 8] = ah1;
        *(short8*)&AsL[aRow][aOff] = al0; *(short8*)&AsL[aRow][aOff + 8] = al1;
        *(short8*)&BsH[aRow][aOff] = bh0; *(short8*)&BsH[aRow][aOff + 8] = bh1;
        *(short8*)&BsL[aRow][aOff] = bl0; *(short8*)&BsL[aRow][aOff + 8] = bl1;
        __syncthreads();

        int k1 = k0 + 32;
        if (k1 < K) {
            const float* aptr;
            if (MODE == 0)
                aptr = (k1 < N_FEAT) ? X + (size_t)mc * N_FEAT + k1 + aOff
                                     : EMB + (size_t)embRow * EMB_DIM + (k1 - N_FEAT) + aOff;
            else
                aptr = X + (size_t)mc * HIDDEN + k1 + aOff;
            *(float4*)&av[0]  = *(const float4*)(aptr);
            *(float4*)&av[4]  = *(const float4*)(aptr + 4);
            *(float4*)&av[8]  = *(const float4*)(aptr + 8);
            *(float4*)&av[12] = *(const float4*)(aptr + 12);
            size_t bo = (size_t)aRow * K + k1 + aOff;
            bh0 = *(const short8*)&WtH[bo]; bh1 = *(const short8*)&WtH[bo + 8];
            bl0 = *(const short8*)&WtL[bo]; bl1 = *(const short8*)&WtL[bo + 8];
        }

        short8 aH[4], aL[4], bH[4], bL[4];
#pragma unroll
        for (int i = 0; i < 4; i++) {
            aH[i] = *(const short8*)&AsH[wm * 64 + i * 16 + fr][fq * 8];
            aL[i] = *(const short8*)&AsL[wm * 64 + i * 16 + fr][fq * 8];
            bH[i] = *(const short8*)&BsH[wn * 64 + i * 16 + fr][fq * 8];
            bL[i] = *(const short8*)&BsL[wn * 64 + i * 16 + fr][fq * 8];
        }

#pragma unroll
        for (int i = 0; i < 4; i++)
#pragma unroll
            for (int j = 0; j < 4; j++)
                acc[i][j] = __builtin_amdgcn_mfma_f32_16x16x32_bf16(aH[i], bH[j], acc[i][j], 0, 0, 0);
#pragma unroll
        for (int i = 0; i < 4; i++)
#pragma unroll
            for (int j = 0; j < 4; j++)
                acc[i][j] = __builtin_amdgcn_mfma_f32_16x16x32_bf16(aH[i], bL[j], acc[i][j], 0, 0, 0);
#pragma unroll
        for (int i = 0; i < 4; i++)
#pragma unroll
            for (int j = 0; j < 4; j++)
                acc[i][j] = __builtin_amdgcn_mfma_f32_16x16x32_bf16(aL[i], bH[j], acc[i][j], 0, 0, 0);
        __syncthreads();
    }

    // epilogue: C/D map col=lane&15, row=(lane>>4)*4+reg ; write bf16
#pragma unroll
    for (int i = 0; i < 4; i++) {
#pragma unroll
        for (int j = 0; j < 4; j++) {
            int gcol = wn * 64 + j * 16 + fr;
#pragma unroll
            for (int r = 0; r < 4; r++) {
                int grow = mBase + wm * 64 + i * 16 + fq * 4 + r;
                if (grow < N_NODES) tbf[(size_t)grow * HIDDEN + gcol] = f2bf(acc[i][j][r]);
            }
        }
    }
}

// ---------------- CSR gather-aggregate (bf16 t), one wave per node ------------------
// acc[n,:] = sum_e norm_e * t[src_e,:] + dinv[n]^2 * t[n,:] + b
// POOL=0: write fp32 row to outp.  POOL=1: relu + per-block LDS pool into sums/counts.
template <int POOL, int NWAVE>
__global__ __launch_bounds__(NWAVE * 64) void k_agg(const int2* __restrict__ csr,
                                                    const int* __restrict__ rowptr,
                                                    const float* __restrict__ dinv,
                                                    const unsigned short* __restrict__ tbf,
                                                    const float* __restrict__ bias,
                                                    const int* __restrict__ batch,
                                                    float* __restrict__ outp,
                                                    float* __restrict__ sums,
                                                    float* __restrict__ counts) {
    __shared__ float lsum[HIDDEN];
    __shared__ int lcnt;
    const int wv = threadIdx.x >> 6;
    const int lane = threadIdx.x & 63;
    const int n = blockIdx.x * NWAVE + wv;
    const unsigned int* t32 = (const unsigned int*)tbf;  // dword view: row n at n*64

    if (POOL) {
        if (threadIdx.x < HIDDEN) lsum[threadIdx.x] = 0.f;
        if (threadIdx.x == 0) lcnt = 0;
        __syncthreads();
    }

    float2 a = {0.f, 0.f};
    if (n < N_NODES) {
        const int beg = rowptr[n];
        const int end = rowptr[n + 1];
        const float di = dinv[n];
        const float sc = di * di;
        unsigned int sv = t32[(size_t)n * 64 + lane];
        float2 bv = ((const float2*)bias)[lane];
        a.x = fmaf(sc, bflo(sv), bv.x);
        a.y = fmaf(sc, bfhi(sv), bv.y);

        for (int base = beg; base < end; base += 64) {
            int cnt = end - base; if (cnt > 64) cnt = 64;
            int2 ce = (lane < cnt) ? csr[base + lane] : make_int2(0, 0);
            int j = 0;
            for (; j + 4 <= cnt; j += 4) {
                int s0 = __shfl(ce.x, j),     s1 = __shfl(ce.x, j + 1);
                int s2 = __shfl(ce.x, j + 2), s3 = __shfl(ce.x, j + 3);
                float w0 = __int_as_float(__shfl(ce.y, j));
                float w1 = __int_as_float(__shfl(ce.y, j + 1));
                float w2 = __int_as_float(__shfl(ce.y, j + 2));
                float w3 = __int_as_float(__shfl(ce.y, j + 3));
                unsigned int r0 = t32[(size_t)s0 * 64 + lane];
                unsigned int r1 = t32[(size_t)s1 * 64 + lane];
                unsigned int r2 = t32[(size_t)s2 * 64 + lane];
                unsigned int r3 = t32[(size_t)s3 * 64 + lane];
                a.x = fmaf(w0, bflo(r0), a.x); a.y = fmaf(w0, bfhi(r0), a.y);
                a.x = fmaf(w1, bflo(r1), a.x); a.y = fmaf(w1, bfhi(r1), a.y);
                a.x = fmaf(w2, bflo(r2), a.x); a.y = fmaf(w2, bfhi(r2), a.y);
                a.x = fmaf(w3, bflo(r3), a.x); a.y = fmaf(w3, bfhi(r3), a.y);
            }
            for (; j < cnt; j++) {
                int s0 = __shfl(ce.x, j);
                float w0 = __int_as_float(__shfl(ce.y, j));
                unsigned int r0 = t32[(size_t)s0 * 64 + lane];
                a.x = fmaf(w0, bflo(r0), a.x); a.y = fmaf(w0, bfhi(r0), a.y);
            }
        }
    }

    if (!POOL) {
        if (n < N_NODES) ((float2*)(outp + (size_t)n * HIDDEN))[lane] = a;
    } else {
        if (n < N_NODES) {
            a.x = fmaxf(a.x, 0.f);
            a.y = fmaxf(a.y, 0.f);
            int g = batch[n];
            int g0 = batch[blockIdx.x * NWAVE];  // block's leading graph
            if (g == g0) {
                atomicAdd(&lsum[lane * 2], a.x);
                atomicAdd(&lsum[lane * 2 + 1], a.y);
                if (lane == 0) atomicAdd(&lcnt, 1);
            } else {  // rare boundary wave: direct global
                atomicAdd(&sums[g * HIDDEN + lane * 2], a.x);
                atomicAdd(&sums[g * HIDDEN + lane * 2 + 1], a.y);
                if (lane == 0) atomicAdd(&counts[g], 1.0f);
            }
        }
        __syncthreads();
        int g0 = batch[blockIdx.x * NWAVE];
        if (threadIdx.x < HIDDEN) atomicAdd(&sums[g0 * HIDDEN + threadIdx.x], lsum[threadIdx.x]);
        if (threadIdx.x == 0) atomicAdd(&counts[g0], (float)lcnt);
    }
}

// ---------------- final: out[g,o] = (sums[g,:]/max(cnt,1)) @ fcW + fcb -------------
__global__ __launch_bounds__(64) void k_final(const float* __restrict__ sums,
                                              const float* __restrict__ counts,
                                              const float* __restrict__ fcW,
                                              const float* __restrict__ fcb,
                                              float* __restrict__ out) {
    int g = blockIdx.x;
    int o = threadIdx.x;
    if (o >= OUT_DIM) return;
    float inv = 1.0f / fmaxf(counts[g], 1.0f);
    float acc = 0.f;
    for (int f = 0; f < HIDDEN; f++)
        acc = fmaf(sums[g * HIDDEN + f], fcW[f * OUT_DIM + o], acc);
    out[g * OUT_DIM + o] = acc * inv + fcb[o];
}

extern "C" void kernel_launch(void* const* d_in, const int* in_sizes, int n_in,
                              void* d_out, int out_size, void* d_ws, size_t ws_size,
                              hipStream_t stream) {
    const float* x      = (const float*)d_in[0];
    const float* ew     = (const float*)d_in[1];
    const float* emb    = (const float*)d_in[2];
    const float* W1     = (const float*)d_in[3];
    const float* b1     = (const float*)d_in[4];
    const float* W2     = (const float*)d_in[5];
    const float* b2     = (const float*)d_in[6];
    const float* fcW    = (const float*)d_in[7];
    const float* fcb    = (const float*)d_in[8];
    const int* edge_idx = (const int*)d_in[9];
    const int* batch    = (const int*)d_in[10];
    const int* node_ids = (const int*)d_in[11];
    float* out = (float*)d_out;

    const int* src = edge_idx;             // edge_index[0]
    const int* dst = edge_idx + N_EDGES;   // edge_index[1]

    // workspace layout (float units; 16B alignment where short8 stores land)
    float* ws     = (float*)d_ws;
    float* dinv   = ws;                                  // 50048
    int*   cntcur = (int*)(ws + 50048);                  // 50048
    int*   rowptr = (int*)(ws + 100096);                 // 50056
    int2*  csr    = (int2*)(ws + 150152);                // 500000 int2 (8B-aligned)
    unsigned short* tbf = (unsigned short*)(ws + 1150152);  // 50000*128 bf16 = 3.2M floats
    float* out1   = ws + 4350152;                        // 6.4M fp32
    float* sums   = out1 + 6400000;                      // 8192
    float* counts = sums + N_GRAPHS * HIDDEN;            // 64
    unsigned short* wtH1 = (unsigned short*)(ws + 10758408);  // 128*1152
    unsigned short* wtL1 = (unsigned short*)(ws + 10832136);
    unsigned short* wtH2 = (unsigned short*)(ws + 10905864);  // 128*128
    unsigned short* wtL2 = (unsigned short*)(ws + 10914056);
    // end ~10922248 floats = 43.7 MB

    const int NB_NODE = (N_NODES + 255) / 256;           // 196
    const int NB_EDGE = (N_EDGES + 255) / 256;           // 1954
    const int NB_GEMM = (N_NODES + 127) / 128;           // 391
    const int K1 = N_FEAT + EMB_DIM;                     // 1152

    // preprocessing: degrees, dinv, CSR, weight split (5 launches)
    k_init<<<NB_NODE, 256, 0, stream>>>(dinv, cntcur, sums, counts);
    k_deg <<<NB_EDGE, 256, 0, stream>>>(dst, ew, dinv, cntcur);
    k_scan<<<1, SCAN_T, 0, stream>>>(cntcur, rowptr, dinv);
    k_fill<<<NB_EDGE, 256, 0, stream>>>(src, dst, ew, dinv, cntcur, csr);
    k_prep<<<40, 256, 0, stream>>>(W1, wtH1, wtL1, W2, wtH2, wtL2);

    // conv1: t1 = [x|emb] @ W1 (bf16) ; out1 = csr-aggregate + self + b1 (fp32)
    k_gemm<0><<<NB_GEMM, 256, 0, stream>>>(x, emb, node_ids, wtH1, wtL1, tbf, K1);
    k_agg<0, 4><<<(N_NODES + 3) / 4, 256, 0, stream>>>(csr, rowptr, dinv, tbf, b1,
                                                       batch, out1, sums, counts);

    // conv2: t2 = relu(out1) @ W2 (bf16) ; fused aggregate+relu+pool
    k_gemm<1><<<NB_GEMM, 256, 0, stream>>>(out1, nullptr, nullptr, wtH2, wtL2, tbf, HIDDEN);
    k_agg<1, 16><<<(N_NODES + 15) / 16, 1024, 0, stream>>>(csr, rowptr, dinv, tbf, b2,
                                                           batch, nullptr, sums, counts);

    // classifier
    k_final<<<N_GRAPHS, 64, 0, stream>>>(sums, counts, fcW, fcb, out);
}

// Round 5
// 555.340 us; speedup vs baseline: 1.9797x; 1.2507x over previous
//
#include <hip/hip_runtime.h>
#include <hip/hip_bf16.h>

#define N_NODES 50000
#define N_EDGES 500000
#define N_FEAT 128
#define EMB_DIM 1024
#define HIDDEN 128
#define OUT_DIM 10
#define N_GRAPHS 64
#define NB_NODE 196   // ceil(N_NODES/256)

typedef __attribute__((ext_vector_type(8))) short short8;   // 8 bf16 = 4 VGPR (MFMA A/B frag)
typedef __attribute__((ext_vector_type(4))) float f32x4;    // MFMA C/D frag

// ---- fp32 -> bf16 RTN-even (finite inputs), and back ----
__device__ __forceinline__ unsigned short f2bf(float f) {
    unsigned int u = __float_as_uint(f);
    return (unsigned short)((u + 0x7fffu + ((u >> 16) & 1u)) >> 16);
}
__device__ __forceinline__ float bf2f(unsigned short h) {
    return __uint_as_float(((unsigned int)h) << 16);
}
// unpack a dword holding 2 bf16 (elements 2k, 2k+1)
__device__ __forceinline__ float bflo(unsigned int r) { return __uint_as_float(r << 16); }
__device__ __forceinline__ float bfhi(unsigned int r) { return __uint_as_float(r & 0xffff0000u); }

// ---------------- init: deg=1 (self loop), cnt=0, zero pool buffers ----------------
__global__ __launch_bounds__(256) void k_init(float* __restrict__ deg,
                                              int* __restrict__ cnt,
                                              float* __restrict__ sums,
                                              float* __restrict__ counts) {
    int i = blockIdx.x * 256 + threadIdx.x;
    if (i < N_NODES) { deg[i] = 1.0f; cnt[i] = 0; }
    if (i < N_GRAPHS * HIDDEN) sums[i] = 0.0f;
    if (i < N_GRAPHS) counts[i] = 0.0f;
}

// ---------------- degree scatter: weighted deg (float) + in-degree count (int) ------
__global__ __launch_bounds__(256) void k_deg(const int* __restrict__ dst,
                                             const float* __restrict__ ew,
                                             float* __restrict__ deg,
                                             int* __restrict__ cnt) {
    int e = blockIdx.x * 256 + threadIdx.x;
    if (e < N_EDGES) {
        int d = dst[e];
        atomicAdd(&deg[d], ew[e]);
        atomicAdd(&cnt[d], 1);
    }
}

// ---------------- scan pass 1: per-block (256 nodes) reduce of cnt ----------------
__global__ __launch_bounds__(256) void k_scan1(const int* __restrict__ cnt,
                                               int* __restrict__ bsum) {
    __shared__ int wsum[4];
    int i = blockIdx.x * 256 + threadIdx.x;
    int v = (i < N_NODES) ? cnt[i] : 0;
#pragma unroll
    for (int off = 32; off; off >>= 1) v += __shfl_down(v, off, 64);
    if ((threadIdx.x & 63) == 0) wsum[threadIdx.x >> 6] = v;
    __syncthreads();
    if (threadIdx.x == 0) bsum[blockIdx.x] = wsum[0] + wsum[1] + wsum[2] + wsum[3];
}

// ---------------- scan pass 2: exclusive scan of NB_NODE block sums (1 block) ------
__global__ __launch_bounds__(256) void k_scan2(int* __restrict__ bsum) {
    __shared__ int sh[256];
    int t = threadIdx.x;
    int v = (t < NB_NODE) ? bsum[t] : 0;
    sh[t] = v;
    __syncthreads();
    for (int off = 1; off < 256; off <<= 1) {
        int add = (t >= off) ? sh[t - off] : 0;
        __syncthreads();
        sh[t] += add;
        __syncthreads();
    }
    if (t < NB_NODE) bsum[t] = sh[t] - v;  // exclusive
}

// ---------------- scan pass 3: per-block exclusive scan + offset; dinv fused -------
// cntcur: in = cnt, out = cursor start (= rowptr).
__global__ __launch_bounds__(256) void k_scan3(int* __restrict__ cntcur,
                                               const int* __restrict__ bofs,
                                               int* __restrict__ rowptr,
                                               float* __restrict__ dinv) {
    __shared__ int sh[256];
    const int t = threadIdx.x;
    const int i = blockIdx.x * 256 + t;
    int v = (i < N_NODES) ? cntcur[i] : 0;
    sh[t] = v;
    __syncthreads();
    for (int off = 1; off < 256; off <<= 1) {
        int add = (t >= off) ? sh[t - off] : 0;
        __syncthreads();
        sh[t] += add;
        __syncthreads();
    }
    int ex = sh[t] - v + bofs[blockIdx.x];
    if (i < N_NODES) {
        rowptr[i] = ex;
        cntcur[i] = ex;                       // cursor start
        dinv[i] = 1.0f / sqrtf(dinv[i]);      // deg >= 1 (self loop)
    }
    if (i == 0) rowptr[N_NODES] = N_EDGES;
}

// ---------------- fill CSR: csr[pos] = (src, norm) ----------------
__global__ __launch_bounds__(256) void k_fill(const int* __restrict__ src,
                                              const int* __restrict__ dst,
                                              const float* __restrict__ ew,
                                              const float* __restrict__ dinv,
                                              int* __restrict__ cursor,
                                              int2* __restrict__ csr) {
    int e = blockIdx.x * 256 + threadIdx.x;
    if (e >= N_EDGES) return;
    int s = src[e], d = dst[e];
    int pos = atomicAdd(&cursor[d], 1);
    float norm = dinv[s] * ew[e] * dinv[d];
    csr[pos] = make_int2(s, __float_as_int(norm));
}

// ---------------- W (K x 128) -> Wt (128 x K) split to bf16 hi/lo (both W1, W2) ----
__device__ __forceinline__ void prep_one(const float* __restrict__ W,
                                         unsigned short* __restrict__ WtH,
                                         unsigned short* __restrict__ WtL,
                                         int K, int t) {
    int n = t & 127;
    int c = t >> 7;
    if (c * 16 >= K) return;
    short8 h0, h1, l0, l1;
#pragma unroll
    for (int i = 0; i < 16; i++) {
        float v = W[(size_t)(c * 16 + i) * HIDDEN + n];
        unsigned short h = f2bf(v);
        unsigned short l = f2bf(v - bf2f(h));
        if (i < 8) { h0[i] = (short)h; l0[i] = (short)l; }
        else       { h1[i - 8] = (short)h; l1[i - 8] = (short)l; }
    }
    size_t o = (size_t)n * K + c * 16;
    *(short8*)&WtH[o] = h0; *(short8*)&WtH[o + 8] = h1;
    *(short8*)&WtL[o] = l0; *(short8*)&WtL[o + 8] = l1;
}

__global__ __launch_bounds__(256) void k_prep(const float* __restrict__ W1,
                                              unsigned short* __restrict__ WtH1,
                                              unsigned short* __restrict__ WtL1,
                                              const float* __restrict__ W2,
                                              unsigned short* __restrict__ WtH2,
                                              unsigned short* __restrict__ WtL2) {
    int b = blockIdx.x;
    if (b < 36) prep_one(W1, WtH1, WtL1, N_FEAT + EMB_DIM, b * 256 + threadIdx.x);
    else        prep_one(W2, WtH2, WtL2, HIDDEN, (b - 36) * 256 + threadIdx.x);
}

// ---------------- split-bf16 MFMA GEMM: tbf[M,128] = A[M,K] @ W[K,128], bf16 out ----
// Block: 128x128, 256 threads (4 waves 2x2), 64x64 per wave, BK=32.
// 3-MFMA combo per tile: aH*bH + aH*bL + aL*bH.
// MODE 0: A row m = [ x[m,0:128] | emb[ids[m],0:1024] ]  (K=1152)
// MODE 1: A row m = relu(X[m,0:128])                      (K=128)
template <int MODE>
__global__ __launch_bounds__(256) void k_gemm(const float* __restrict__ X,
                                              const float* __restrict__ EMB,
                                              const int* __restrict__ ids,
                                              const unsigned short* __restrict__ WtH,
                                              const unsigned short* __restrict__ WtL,
                                              unsigned short* __restrict__ tbf, int K) {
    __shared__ unsigned short AsH[128][40];  // [row][k], stride 40 (80 B, 16B-aligned)
    __shared__ unsigned short AsL[128][40];
    __shared__ unsigned short BsH[128][40];  // [col][k]
    __shared__ unsigned short BsL[128][40];

    const int tid = threadIdx.x;
    const int lane = tid & 63;
    const int wv = tid >> 6;
    const int wm = wv >> 1, wn = wv & 1;     // wave quadrant
    const int fr = lane & 15;                // frag row/col
    const int fq = lane >> 4;                // frag k-octet
    const int mBase = blockIdx.x * 128;

    const int aRow = tid >> 1;
    const int aOff = (tid & 1) * 16;
    const int m = mBase + aRow;
    const int mc = (m < N_NODES) ? m : (N_NODES - 1);
    int embRow = 0;
    if (MODE == 0) embRow = ids[mc];

    f32x4 acc[4][4];
#pragma unroll
    for (int i = 0; i < 4; i++)
#pragma unroll
        for (int j = 0; j < 4; j++) acc[i][j] = (f32x4){0.f, 0.f, 0.f, 0.f};

    // prefetch k0=0 globals
    float av[16];
    short8 bh0, bh1, bl0, bl1;
    {
        const float* aptr = (MODE == 0)
            ? X + (size_t)mc * N_FEAT + aOff
            : X + (size_t)mc * HIDDEN + aOff;
        *(float4*)&av[0]  = *(const float4*)(aptr);
        *(float4*)&av[4]  = *(const float4*)(aptr + 4);
        *(float4*)&av[8]  = *(const float4*)(aptr + 8);
        *(float4*)&av[12] = *(const float4*)(aptr + 12);
        size_t bo = (size_t)aRow * K + aOff;
        bh0 = *(const short8*)&WtH[bo]; bh1 = *(const short8*)&WtH[bo + 8];
        bl0 = *(const short8*)&WtL[bo]; bl1 = *(const short8*)&WtL[bo + 8];
    }

    for (int k0 = 0; k0 < K; k0 += 32) {
        short8 ah0, ah1, al0, al1;
#pragma unroll
        for (int i = 0; i < 16; i++) {
            float v = av[i];
            if (MODE == 1) v = fmaxf(v, 0.f);
            unsigned short h = f2bf(v);
            unsigned short l = f2bf(v - bf2f(h));
            if (i < 8) { ah0[i] = (short)h; al0[i] = (short)l; }
            else       { ah1[i - 8] = (short)h; al1[i - 8] = (short)l; }
        }
        *(short8*)&AsH[aRow][aOff] = ah0; *(short8*)&AsH[aRow][aOff + 8] = ah1;
        *(short8*)&AsL[aRow][aOff] = al0; *(short8*)&AsL[aRow][aOff + 8] = al1;
        *(short8*)&BsH[aRow][aOff] = bh0; *(short8*)&BsH[aRow][aOff + 8] = bh1;
        *(short8*)&BsL[aRow][aOff] = bl0; *(short8*)&BsL[aRow][aOff + 8] = bl1;
        __syncthreads();

        int k1 = k0 + 32;
        if (k1 < K) {
            const float* aptr;
            if (MODE == 0)
                aptr = (k1 < N_FEAT) ? X + (size_t)mc * N_FEAT + k1 + aOff
                                     : EMB + (size_t)embRow * EMB_DIM + (k1 - N_FEAT) + aOff;
            else
                aptr = X + (size_t)mc * HIDDEN + k1 + aOff;
            *(float4*)&av[0]  = *(const float4*)(aptr);
            *(float4*)&av[4]  = *(const float4*)(aptr + 4);
            *(float4*)&av[8]  = *(const float4*)(aptr + 8);
            *(float4*)&av[12] = *(const float4*)(aptr + 12);
            size_t bo = (size_t)aRow * K + k1 + aOff;
            bh0 = *(const short8*)&WtH[bo]; bh1 = *(const short8*)&WtH[bo + 8];
            bl0 = *(const short8*)&WtL[bo]; bl1 = *(const short8*)&WtL[bo + 8];
        }

        short8 aH[4], aL[4], bH[4], bL[4];
#pragma unroll
        for (int i = 0; i < 4; i++) {
            aH[i] = *(const short8*)&AsH[wm * 64 + i * 16 + fr][fq * 8];
            aL[i] = *(const short8*)&AsL[wm * 64 + i * 16 + fr][fq * 8];
            bH[i] = *(const short8*)&BsH[wn * 64 + i * 16 + fr][fq * 8];
            bL[i] = *(const short8*)&BsL[wn * 64 + i * 16 + fr][fq * 8];
        }

#pragma unroll
        for (int i = 0; i < 4; i++)
#pragma unroll
            for (int j = 0; j < 4; j++)
                acc[i][j] = __builtin_amdgcn_mfma_f32_16x16x32_bf16(aH[i], bH[j], acc[i][j], 0, 0, 0);
#pragma unroll
        for (int i = 0; i < 4; i++)
#pragma unroll
            for (int j = 0; j < 4; j++)
                acc[i][j] = __builtin_amdgcn_mfma_f32_16x16x32_bf16(aH[i], bL[j], acc[i][j], 0, 0, 0);
#pragma unroll
        for (int i = 0; i < 4; i++)
#pragma unroll
            for (int j = 0; j < 4; j++)
                acc[i][j] = __builtin_amdgcn_mfma_f32_16x16x32_bf16(aL[i], bH[j], acc[i][j], 0, 0, 0);
        __syncthreads();
    }

    // epilogue: C/D map col=lane&15, row=(lane>>4)*4+reg ; write bf16
#pragma unroll
    for (int i = 0; i < 4; i++) {
#pragma unroll
        for (int j = 0; j < 4; j++) {
            int gcol = wn * 64 + j * 16 + fr;
#pragma unroll
            for (int r = 0; r < 4; r++) {
                int grow = mBase + wm * 64 + i * 16 + fq * 4 + r;
                if (grow < N_NODES) tbf[(size_t)grow * HIDDEN + gcol] = f2bf(acc[i][j][r]);
            }
        }
    }
}

// ---------------- CSR gather-aggregate (bf16 t), one wave per node ------------------
// acc[n,:] = sum_e norm_e * t[src_e,:] + dinv[n]^2 * t[n,:] + b
// POOL=0: write fp32 row to outp.  POOL=1: relu + per-block LDS pool into sums/counts.
template <int POOL, int NWAVE>
__global__ __launch_bounds__(NWAVE * 64) void k_agg(const int2* __restrict__ csr,
                                                    const int* __restrict__ rowptr,
                                                    const float* __restrict__ dinv,
                                                    const unsigned short* __restrict__ tbf,
                                                    const float* __restrict__ bias,
                                                    const int* __restrict__ batch,
                                                    float* __restrict__ outp,
                                                    float* __restrict__ sums,
                                                    float* __restrict__ counts) {
    __shared__ float lsum[HIDDEN];
    __shared__ int lcnt;
    const int wv = threadIdx.x >> 6;
    const int lane = threadIdx.x & 63;
    const int n = blockIdx.x * NWAVE + wv;
    const unsigned int* t32 = (const unsigned int*)tbf;  // dword view: row n at n*64

    if (POOL) {
        if (threadIdx.x < HIDDEN) lsum[threadIdx.x] = 0.f;
        if (threadIdx.x == 0) lcnt = 0;
        __syncthreads();
    }

    float2 a = {0.f, 0.f};
    if (n < N_NODES) {
        const int beg = rowptr[n];
        const int end = rowptr[n + 1];
        const float di = dinv[n];
        const float sc = di * di;
        unsigned int sv = t32[(size_t)n * 64 + lane];
        float2 bv = ((const float2*)bias)[lane];
        a.x = fmaf(sc, bflo(sv), bv.x);
        a.y = fmaf(sc, bfhi(sv), bv.y);

        for (int base = beg; base < end; base += 64) {
            int cnt = end - base; if (cnt > 64) cnt = 64;
            int2 ce = (lane < cnt) ? csr[base + lane] : make_int2(0, 0);
            int j = 0;
            for (; j + 4 <= cnt; j += 4) {
                int s0 = __shfl(ce.x, j),     s1 = __shfl(ce.x, j + 1);
                int s2 = __shfl(ce.x, j + 2), s3 = __shfl(ce.x, j + 3);
                float w0 = __int_as_float(__shfl(ce.y, j));
                float w1 = __int_as_float(__shfl(ce.y, j + 1));
                float w2 = __int_as_float(__shfl(ce.y, j + 2));
                float w3 = __int_as_float(__shfl(ce.y, j + 3));
                unsigned int r0 = t32[(size_t)s0 * 64 + lane];
                unsigned int r1 = t32[(size_t)s1 * 64 + lane];
                unsigned int r2 = t32[(size_t)s2 * 64 + lane];
                unsigned int r3 = t32[(size_t)s3 * 64 + lane];
                a.x = fmaf(w0, bflo(r0), a.x); a.y = fmaf(w0, bfhi(r0), a.y);
                a.x = fmaf(w1, bflo(r1), a.x); a.y = fmaf(w1, bfhi(r1), a.y);
                a.x = fmaf(w2, bflo(r2), a.x); a.y = fmaf(w2, bfhi(r2), a.y);
                a.x = fmaf(w3, bflo(r3), a.x); a.y = fmaf(w3, bfhi(r3), a.y);
            }
            for (; j < cnt; j++) {
                int s0 = __shfl(ce.x, j);
                float w0 = __int_as_float(__shfl(ce.y, j));
                unsigned int r0 = t32[(size_t)s0 * 64 + lane];
                a.x = fmaf(w0, bflo(r0), a.x); a.y = fmaf(w0, bfhi(r0), a.y);
            }
        }
    }

    if (!POOL) {
        if (n < N_NODES) ((float2*)(outp + (size_t)n * HIDDEN))[lane] = a;
    } else {
        if (n < N_NODES) {
            a.x = fmaxf(a.x, 0.f);
            a.y = fmaxf(a.y, 0.f);
            int g = batch[n];
            int g0 = batch[blockIdx.x * NWAVE];  // block's leading graph
            if (g == g0) {
                atomicAdd(&lsum[lane * 2], a.x);
                atomicAdd(&lsum[lane * 2 + 1], a.y);
                if (lane == 0) atomicAdd(&lcnt, 1);
            } else {  // rare boundary wave: direct global
                atomicAdd(&sums[g * HIDDEN + lane * 2], a.x);
                atomicAdd(&sums[g * HIDDEN + lane * 2 + 1], a.y);
                if (lane == 0) atomicAdd(&counts[g], 1.0f);
            }
        }
        __syncthreads();
        int g0 = batch[blockIdx.x * NWAVE];
        if (threadIdx.x < HIDDEN) atomicAdd(&sums[g0 * HIDDEN + threadIdx.x], lsum[threadIdx.x]);
        if (threadIdx.x == 0) atomicAdd(&counts[g0], (float)lcnt);
    }
}

// ---------------- final: out[g,o] = (sums[g,:]/max(cnt,1)) @ fcW + fcb -------------
__global__ __launch_bounds__(64) void k_final(const float* __restrict__ sums,
                                              const float* __restrict__ counts,
                                              const float* __restrict__ fcW,
                                              const float* __restrict__ fcb,
                                              float* __restrict__ out) {
    int g = blockIdx.x;
    int o = threadIdx.x;
    if (o >= OUT_DIM) return;
    float inv = 1.0f / fmaxf(counts[g], 1.0f);
    float acc = 0.f;
    for (int f = 0; f < HIDDEN; f++)
        acc = fmaf(sums[g * HIDDEN + f], fcW[f * OUT_DIM + o], acc);
    out[g * OUT_DIM + o] = acc * inv + fcb[o];
}

extern "C" void kernel_launch(void* const* d_in, const int* in_sizes, int n_in,
                              void* d_out, int out_size, void* d_ws, size_t ws_size,
                              hipStream_t stream) {
    const float* x      = (const float*)d_in[0];
    const float* ew     = (const float*)d_in[1];
    const float* emb    = (const float*)d_in[2];
    const float* W1     = (const float*)d_in[3];
    const float* b1     = (const float*)d_in[4];
    const float* W2     = (const float*)d_in[5];
    const float* b2     = (const float*)d_in[6];
    const float* fcW    = (const float*)d_in[7];
    const float* fcb    = (const float*)d_in[8];
    const int* edge_idx = (const int*)d_in[9];
    const int* batch    = (const int*)d_in[10];
    const int* node_ids = (const int*)d_in[11];
    float* out = (float*)d_out;

    const int* src = edge_idx;             // edge_index[0]
    const int* dst = edge_idx + N_EDGES;   // edge_index[1]

    // workspace layout (float units; 16B alignment where short8 stores land)
    float* ws     = (float*)d_ws;
    float* dinv   = ws;                                  // 50048
    int*   cntcur = (int*)(ws + 50048);                  // 50048
    int*   rowptr = (int*)(ws + 100096);                 // 50056
    int*   bsum   = (int*)(ws + 150152);                 // 256 (block sums)
    int2*  csr    = (int2*)(ws + 150408);                // 500000 int2 (8B-aligned)
    unsigned short* tbf = (unsigned short*)(ws + 1150408);  // 50000*128 bf16 = 3.2M floats
    float* out1   = ws + 4350408;                        // 6.4M fp32
    float* sums   = out1 + 6400000;                      // 8192
    float* counts = sums + N_GRAPHS * HIDDEN;            // 64
    unsigned short* wtH1 = (unsigned short*)(ws + 10758664);  // 128*1152
    unsigned short* wtL1 = (unsigned short*)(ws + 10832392);
    unsigned short* wtH2 = (unsigned short*)(ws + 10906120);  // 128*128
    unsigned short* wtL2 = (unsigned short*)(ws + 10914312);
    // end ~10922504 floats = 43.7 MB

    const int NB_EDGE = (N_EDGES + 255) / 256;           // 1954
    const int NB_GEMM = (N_NODES + 127) / 128;           // 391
    const int K1 = N_FEAT + EMB_DIM;                     // 1152

    // preprocessing: degrees, multi-block scan (rowptr/cursor + dinv), CSR, weights
    k_init <<<NB_NODE, 256, 0, stream>>>(dinv, cntcur, sums, counts);
    k_deg  <<<NB_EDGE, 256, 0, stream>>>(dst, ew, dinv, cntcur);
    k_scan1<<<NB_NODE, 256, 0, stream>>>(cntcur, bsum);
    k_scan2<<<1, 256, 0, stream>>>(bsum);
    k_scan3<<<NB_NODE, 256, 0, stream>>>(cntcur, bsum, rowptr, dinv);
    k_fill <<<NB_EDGE, 256, 0, stream>>>(src, dst, ew, dinv, cntcur, csr);
    k_prep <<<40, 256, 0, stream>>>(W1, wtH1, wtL1, W2, wtH2, wtL2);

    // conv1: t1 = [x|emb] @ W1 (bf16) ; out1 = csr-aggregate + self + b1 (fp32)
    k_gemm<0><<<NB_GEMM, 256, 0, stream>>>(x, emb, node_ids, wtH1, wtL1, tbf, K1);
    k_agg<0, 4><<<(N_NODES + 3) / 4, 256, 0, stream>>>(csr, rowptr, dinv, tbf, b1,
                                                       batch, out1, sums, counts);

    // conv2: t2 = relu(out1) @ W2 (bf16) ; fused aggregate+relu+pool
    k_gemm<1><<<NB_GEMM, 256, 0, stream>>>(out1, nullptr, nullptr, wtH2, wtL2, tbf, HIDDEN);
    k_agg<1, 16><<<(N_NODES + 15) / 16, 1024, 0, stream>>>(csr, rowptr, dinv, tbf, b2,
                                                           batch, nullptr, sums, counts);

    // classifier
    k_final<<<N_GRAPHS, 64, 0, stream>>>(sums, counts, fcW, fcb, out);
}

// Round 6
// 549.049 us; speedup vs baseline: 2.0024x; 1.0115x over previous
//
#include <hip/hip_runtime.h>
#include <hip/hip_bf16.h>

#define N_NODES 50000
#define N_EDGES 500000
#define N_FEAT 128
#define EMB_DIM 1024
#define HIDDEN 128
#define OUT_DIM 10
#define N_GRAPHS 64
#define NB_NODE 196   // ceil(N_NODES/256)

typedef __attribute__((ext_vector_type(8))) short short8;   // 8 bf16 = 4 VGPR (MFMA A/B frag)
typedef __attribute__((ext_vector_type(4))) float f32x4;    // MFMA C/D frag

// ---- fp32 -> bf16 RTN-even (finite inputs), and back ----
__device__ __forceinline__ unsigned short f2bf(float f) {
    unsigned int u = __float_as_uint(f);
    return (unsigned short)((u + 0x7fffu + ((u >> 16) & 1u)) >> 16);
}
// unpack a dword holding 2 bf16 (elements 2k, 2k+1)
__device__ __forceinline__ float bflo(unsigned int r) { return __uint_as_float(r << 16); }
__device__ __forceinline__ float bfhi(unsigned int r) { return __uint_as_float(r & 0xffff0000u); }

// ---------------- init: deg=1 (self loop), cnt=0, zero pool buffers ----------------
__global__ __launch_bounds__(256) void k_init(float* __restrict__ deg,
                                              int* __restrict__ cnt,
                                              float* __restrict__ sums,
                                              float* __restrict__ counts) {
    int i = blockIdx.x * 256 + threadIdx.x;
    if (i < N_NODES) { deg[i] = 1.0f; cnt[i] = 0; }
    if (i < N_GRAPHS * HIDDEN) sums[i] = 0.0f;
    if (i < N_GRAPHS) counts[i] = 0.0f;
}

// ---------------- degree scatter: weighted deg (float) + in-degree count (int) ------
__global__ __launch_bounds__(256) void k_deg(const int* __restrict__ dst,
                                             const float* __restrict__ ew,
                                             float* __restrict__ deg,
                                             int* __restrict__ cnt) {
    int e = blockIdx.x * 256 + threadIdx.x;
    if (e < N_EDGES) {
        int d = dst[e];
        atomicAdd(&deg[d], ew[e]);
        atomicAdd(&cnt[d], 1);
    }
}

// ---------------- scan pass 1: per-block (256 nodes) reduce of cnt ----------------
__global__ __launch_bounds__(256) void k_scan1(const int* __restrict__ cnt,
                                               int* __restrict__ bsum) {
    __shared__ int wsum[4];
    int i = blockIdx.x * 256 + threadIdx.x;
    int v = (i < N_NODES) ? cnt[i] : 0;
#pragma unroll
    for (int off = 32; off; off >>= 1) v += __shfl_down(v, off, 64);
    if ((threadIdx.x & 63) == 0) wsum[threadIdx.x >> 6] = v;
    __syncthreads();
    if (threadIdx.x == 0) bsum[blockIdx.x] = wsum[0] + wsum[1] + wsum[2] + wsum[3];
}

// ---------------- scan pass 2: exclusive scan of NB_NODE block sums (1 block) ------
__global__ __launch_bounds__(256) void k_scan2(int* __restrict__ bsum) {
    __shared__ int sh[256];
    int t = threadIdx.x;
    int v = (t < NB_NODE) ? bsum[t] : 0;
    sh[t] = v;
    __syncthreads();
    for (int off = 1; off < 256; off <<= 1) {
        int add = (t >= off) ? sh[t - off] : 0;
        __syncthreads();
        sh[t] += add;
        __syncthreads();
    }
    if (t < NB_NODE) bsum[t] = sh[t] - v;  // exclusive
}

// ---------------- scan pass 3: per-block exclusive scan + offset; dinv fused -------
__global__ __launch_bounds__(256) void k_scan3(int* __restrict__ cntcur,
                                               const int* __restrict__ bofs,
                                               int* __restrict__ rowptr,
                                               float* __restrict__ dinv) {
    __shared__ int sh[256];
    const int t = threadIdx.x;
    const int i = blockIdx.x * 256 + t;
    int v = (i < N_NODES) ? cntcur[i] : 0;
    sh[t] = v;
    __syncthreads();
    for (int off = 1; off < 256; off <<= 1) {
        int add = (t >= off) ? sh[t - off] : 0;
        __syncthreads();
        sh[t] += add;
        __syncthreads();
    }
    int ex = sh[t] - v + bofs[blockIdx.x];
    if (i < N_NODES) {
        rowptr[i] = ex;
        cntcur[i] = ex;                       // cursor start
        dinv[i] = 1.0f / sqrtf(dinv[i]);      // deg >= 1 (self loop)
    }
    if (i == 0) rowptr[N_NODES] = N_EDGES;
}

// ---------------- fill CSR: csr[pos] = (src, norm) ----------------
__global__ __launch_bounds__(256) void k_fill(const int* __restrict__ src,
                                              const int* __restrict__ dst,
                                              const float* __restrict__ ew,
                                              const float* __restrict__ dinv,
                                              int* __restrict__ cursor,
                                              int2* __restrict__ csr) {
    int e = blockIdx.x * 256 + threadIdx.x;
    if (e >= N_EDGES) return;
    int s = src[e], d = dst[e];
    int pos = atomicAdd(&cursor[d], 1);
    float norm = dinv[s] * ew[e] * dinv[d];
    csr[pos] = make_int2(s, __float_as_int(norm));
}

// ---------------- W (K x 128) -> Wt (128 x K) bf16 (both W1, W2) ----------------
__device__ __forceinline__ void prep_one(const float* __restrict__ W,
                                         unsigned short* __restrict__ Wt,
                                         int K, int t) {
    int n = t & 127;
    int c = t >> 7;
    if (c * 16 >= K) return;
    short8 h0, h1;
#pragma unroll
    for (int i = 0; i < 16; i++) {
        unsigned short h = f2bf(W[(size_t)(c * 16 + i) * HIDDEN + n]);
        if (i < 8) h0[i] = (short)h;
        else       h1[i - 8] = (short)h;
    }
    size_t o = (size_t)n * K + c * 16;
    *(short8*)&Wt[o] = h0;
    *(short8*)&Wt[o + 8] = h1;
}

__global__ __launch_bounds__(256) void k_prep(const float* __restrict__ W1,
                                              unsigned short* __restrict__ Wt1,
                                              const float* __restrict__ W2,
                                              unsigned short* __restrict__ Wt2) {
    int b = blockIdx.x;
    if (b < 36) prep_one(W1, Wt1, N_FEAT + EMB_DIM, b * 256 + threadIdx.x);
    else        prep_one(W2, Wt2, HIDDEN, (b - 36) * 256 + threadIdx.x);
}

// ---------------- bf16 MFMA GEMM: tbf[M,128] = A[M,K] @ W[K,128], bf16 out ----------
// Block: 128x128, 256 threads (4 waves 2x2), 64x64 per wave, BK=32, fp32 accum.
// Numerics: A and W rounded to bf16 (error ~0.4% rel, below tbf storage noise).
// MODE 0: A row m = [ x[m,0:128] | emb[ids[m],0:1024] ]  (K=1152)
// MODE 1: A row m = relu(X[m,0:128])                      (K=128)
template <int MODE>
__global__ __launch_bounds__(256) void k_gemm(const float* __restrict__ X,
                                              const float* __restrict__ EMB,
                                              const int* __restrict__ ids,
                                              const unsigned short* __restrict__ Wt,
                                              unsigned short* __restrict__ tbf, int K) {
    __shared__ unsigned short As[128][40];  // [row][k], stride 40 (80 B, 16B-aligned)
    __shared__ unsigned short Bs[128][40];  // [col][k]

    const int tid = threadIdx.x;
    const int lane = tid & 63;
    const int wv = tid >> 6;
    const int wm = wv >> 1, wn = wv & 1;     // wave quadrant
    const int fr = lane & 15;                // frag row/col
    const int fq = lane >> 4;                // frag k-octet
    const int mBase = blockIdx.x * 128;

    const int aRow = tid >> 1;
    const int aOff = (tid & 1) * 16;
    const int m = mBase + aRow;
    const int mc = (m < N_NODES) ? m : (N_NODES - 1);
    int embRow = 0;
    if (MODE == 0) embRow = ids[mc];

    f32x4 acc[4][4];
#pragma unroll
    for (int i = 0; i < 4; i++)
#pragma unroll
        for (int j = 0; j < 4; j++) acc[i][j] = (f32x4){0.f, 0.f, 0.f, 0.f};

    // prefetch k0=0 globals
    float av[16];
    short8 bh0, bh1;
    {
        const float* aptr = (MODE == 0)
            ? X + (size_t)mc * N_FEAT + aOff
            : X + (size_t)mc * HIDDEN + aOff;
        *(float4*)&av[0]  = *(const float4*)(aptr);
        *(float4*)&av[4]  = *(const float4*)(aptr + 4);
        *(float4*)&av[8]  = *(const float4*)(aptr + 8);
        *(float4*)&av[12] = *(const float4*)(aptr + 12);
        size_t bo = (size_t)aRow * K + aOff;
        bh0 = *(const short8*)&Wt[bo];
        bh1 = *(const short8*)&Wt[bo + 8];
    }

    for (int k0 = 0; k0 < K; k0 += 32) {
        // convert A regs to bf16, commit staged regs to LDS
        short8 ah0, ah1;
#pragma unroll
        for (int i = 0; i < 16; i++) {
            float v = av[i];
            if (MODE == 1) v = fmaxf(v, 0.f);
            unsigned short h = f2bf(v);
            if (i < 8) ah0[i] = (short)h;
            else       ah1[i - 8] = (short)h;
        }
        *(short8*)&As[aRow][aOff] = ah0; *(short8*)&As[aRow][aOff + 8] = ah1;
        *(short8*)&Bs[aRow][aOff] = bh0; *(short8*)&Bs[aRow][aOff + 8] = bh1;
        __syncthreads();

        // prefetch next k-step globals (hidden behind MFMAs)
        int k1 = k0 + 32;
        if (k1 < K) {
            const float* aptr;
            if (MODE == 0)
                aptr = (k1 < N_FEAT) ? X + (size_t)mc * N_FEAT + k1 + aOff
                                     : EMB + (size_t)embRow * EMB_DIM + (k1 - N_FEAT) + aOff;
            else
                aptr = X + (size_t)mc * HIDDEN + k1 + aOff;
            *(float4*)&av[0]  = *(const float4*)(aptr);
            *(float4*)&av[4]  = *(const float4*)(aptr + 4);
            *(float4*)&av[8]  = *(const float4*)(aptr + 8);
            *(float4*)&av[12] = *(const float4*)(aptr + 12);
            size_t bo = (size_t)aRow * K + k1 + aOff;
            bh0 = *(const short8*)&Wt[bo];
            bh1 = *(const short8*)&Wt[bo + 8];
        }

        // fragment loads (k = fq*8 + j across the octet)
        short8 aF[4], bF[4];
#pragma unroll
        for (int i = 0; i < 4; i++) {
            aF[i] = *(const short8*)&As[wm * 64 + i * 16 + fr][fq * 8];
            bF[i] = *(const short8*)&Bs[wn * 64 + i * 16 + fr][fq * 8];
        }

#pragma unroll
        for (int i = 0; i < 4; i++)
#pragma unroll
            for (int j = 0; j < 4; j++)
                acc[i][j] = __builtin_amdgcn_mfma_f32_16x16x32_bf16(aF[i], bF[j], acc[i][j], 0, 0, 0);
        __syncthreads();
    }

    // epilogue: C/D map col=lane&15, row=(lane>>4)*4+reg ; write bf16
#pragma unroll
    for (int i = 0; i < 4; i++) {
#pragma unroll
        for (int j = 0; j < 4; j++) {
            int gcol = wn * 64 + j * 16 + fr;
#pragma unroll
            for (int r = 0; r < 4; r++) {
                int grow = mBase + wm * 64 + i * 16 + fq * 4 + r;
                if (grow < N_NODES) tbf[(size_t)grow * HIDDEN + gcol] = f2bf(acc[i][j][r]);
            }
        }
    }
}

// ---------------- CSR gather-aggregate (bf16 t), one wave per node ------------------
// acc[n,:] = sum_e norm_e * t[src_e,:] + dinv[n]^2 * t[n,:] + b
// POOL=0: write fp32 row to outp.  POOL=1: relu + per-block LDS pool into sums/counts.
template <int POOL, int NWAVE>
__global__ __launch_bounds__(NWAVE * 64) void k_agg(const int2* __restrict__ csr,
                                                    const int* __restrict__ rowptr,
                                                    const float* __restrict__ dinv,
                                                    const unsigned short* __restrict__ tbf,
                                                    const float* __restrict__ bias,
                                                    const int* __restrict__ batch,
                                                    float* __restrict__ outp,
                                                    float* __restrict__ sums,
                                                    float* __restrict__ counts) {
    __shared__ float lsum[HIDDEN];
    __shared__ int lcnt;
    const int wv = threadIdx.x >> 6;
    const int lane = threadIdx.x & 63;
    const int n = blockIdx.x * NWAVE + wv;
    const unsigned int* t32 = (const unsigned int*)tbf;  // dword view: row n at n*64

    if (POOL) {
        if (threadIdx.x < HIDDEN) lsum[threadIdx.x] = 0.f;
        if (threadIdx.x == 0) lcnt = 0;
        __syncthreads();
    }

    float2 a = {0.f, 0.f};
    if (n < N_NODES) {
        const int beg = rowptr[n];
        const int end = rowptr[n + 1];
        const float di = dinv[n];
        const float sc = di * di;
        unsigned int sv = t32[(size_t)n * 64 + lane];
        float2 bv = ((const float2*)bias)[lane];
        a.x = fmaf(sc, bflo(sv), bv.x);
        a.y = fmaf(sc, bfhi(sv), bv.y);

        for (int base = beg; base < end; base += 64) {
            int cnt = end - base; if (cnt > 64) cnt = 64;
            int2 ce = (lane < cnt) ? csr[base + lane] : make_int2(0, 0);
            int j = 0;
            for (; j + 4 <= cnt; j += 4) {
                int s0 = __shfl(ce.x, j),     s1 = __shfl(ce.x, j + 1);
                int s2 = __shfl(ce.x, j + 2), s3 = __shfl(ce.x, j + 3);
                float w0 = __int_as_float(__shfl(ce.y, j));
                float w1 = __int_as_float(__shfl(ce.y, j + 1));
                float w2 = __int_as_float(__shfl(ce.y, j + 2));
                float w3 = __int_as_float(__shfl(ce.y, j + 3));
                unsigned int r0 = t32[(size_t)s0 * 64 + lane];
                unsigned int r1 = t32[(size_t)s1 * 64 + lane];
                unsigned int r2 = t32[(size_t)s2 * 64 + lane];
                unsigned int r3 = t32[(size_t)s3 * 64 + lane];
                a.x = fmaf(w0, bflo(r0), a.x); a.y = fmaf(w0, bfhi(r0), a.y);
                a.x = fmaf(w1, bflo(r1), a.x); a.y = fmaf(w1, bfhi(r1), a.y);
                a.x = fmaf(w2, bflo(r2), a.x); a.y = fmaf(w2, bfhi(r2), a.y);
                a.x = fmaf(w3, bflo(r3), a.x); a.y = fmaf(w3, bfhi(r3), a.y);
            }
            for (; j < cnt; j++) {
                int s0 = __shfl(ce.x, j);
                float w0 = __int_as_float(__shfl(ce.y, j));
                unsigned int r0 = t32[(size_t)s0 * 64 + lane];
                a.x = fmaf(w0, bflo(r0), a.x); a.y = fmaf(w0, bfhi(r0), a.y);
            }
        }
    }

    if (!POOL) {
        if (n < N_NODES) ((float2*)(outp + (size_t)n * HIDDEN))[lane] = a;
    } else {
        if (n < N_NODES) {
            a.x = fmaxf(a.x, 0.f);
            a.y = fmaxf(a.y, 0.f);
            int g = batch[n];
            int g0 = batch[blockIdx.x * NWAVE];  // block's leading graph
            if (g == g0) {
                atomicAdd(&lsum[lane * 2], a.x);
                atomicAdd(&lsum[lane * 2 + 1], a.y);
                if (lane == 0) atomicAdd(&lcnt, 1);
            } else {  // rare boundary wave: direct global
                atomicAdd(&sums[g * HIDDEN + lane * 2], a.x);
                atomicAdd(&sums[g * HIDDEN + lane * 2 + 1], a.y);
                if (lane == 0) atomicAdd(&counts[g], 1.0f);
            }
        }
        __syncthreads();
        int g0 = batch[blockIdx.x * NWAVE];
        if (threadIdx.x < HIDDEN) atomicAdd(&sums[g0 * HIDDEN + threadIdx.x], lsum[threadIdx.x]);
        if (threadIdx.x == 0) atomicAdd(&counts[g0], (float)lcnt);
    }
}

// ---------------- final: out[g,o] = (sums[g,:]/max(cnt,1)) @ fcW + fcb -------------
__global__ __launch_bounds__(64) void k_final(const float* __restrict__ sums,
                                              const float* __restrict__ counts,
                                              const float* __restrict__ fcW,
                                              const float* __restrict__ fcb,
                                              float* __restrict__ out) {
    int g = blockIdx.x;
    int o = threadIdx.x;
    if (o >= OUT_DIM) return;
    float inv = 1.0f / fmaxf(counts[g], 1.0f);
    float acc = 0.f;
    for (int f = 0; f < HIDDEN; f++)
        acc = fmaf(sums[g * HIDDEN + f], fcW[f * OUT_DIM + o], acc);
    out[g * OUT_DIM + o] = acc * inv + fcb[o];
}

extern "C" void kernel_launch(void* const* d_in, const int* in_sizes, int n_in,
                              void* d_out, int out_size, void* d_ws, size_t ws_size,
                              hipStream_t stream) {
    const float* x      = (const float*)d_in[0];
    const float* ew     = (const float*)d_in[1];
    const float* emb    = (const float*)d_in[2];
    const float* W1     = (const float*)d_in[3];
    const float* b1     = (const float*)d_in[4];
    const float* W2     = (const float*)d_in[5];
    const float* b2     = (const float*)d_in[6];
    const float* fcW    = (const float*)d_in[7];
    const float* fcb    = (const float*)d_in[8];
    const int* edge_idx = (const int*)d_in[9];
    const int* batch    = (const int*)d_in[10];
    const int* node_ids = (const int*)d_in[11];
    float* out = (float*)d_out;

    const int* src = edge_idx;             // edge_index[0]
    const int* dst = edge_idx + N_EDGES;   // edge_index[1]

    // workspace layout (float units; 16B alignment where short8 stores land)
    float* ws     = (float*)d_ws;
    float* dinv   = ws;                                  // 50048
    int*   cntcur = (int*)(ws + 50048);                  // 50048
    int*   rowptr = (int*)(ws + 100096);                 // 50056
    int*   bsum   = (int*)(ws + 150152);                 // 256 (block sums)
    int2*  csr    = (int2*)(ws + 150408);                // 500000 int2 (8B-aligned)
    unsigned short* tbf = (unsigned short*)(ws + 1150408);  // 50000*128 bf16
    float* out1   = ws + 4350408;                        // 6.4M fp32
    float* sums   = out1 + 6400000;                      // 8192
    float* counts = sums + N_GRAPHS * HIDDEN;            // 64
    unsigned short* wt1 = (unsigned short*)(ws + 10758664);  // 128*1152 bf16
    unsigned short* wt2 = (unsigned short*)(ws + 10832392);  // 128*128 bf16
    // end ~10840584 floats = 43.4 MB

    const int NB_EDGE = (N_EDGES + 255) / 256;           // 1954
    const int NB_GEMM = (N_NODES + 127) / 128;           // 391
    const int K1 = N_FEAT + EMB_DIM;                     // 1152

    // preprocessing: degrees, multi-block scan (rowptr/cursor + dinv), CSR, weights
    k_init <<<NB_NODE, 256, 0, stream>>>(dinv, cntcur, sums, counts);
    k_deg  <<<NB_EDGE, 256, 0, stream>>>(dst, ew, dinv, cntcur);
    k_scan1<<<NB_NODE, 256, 0, stream>>>(cntcur, bsum);
    k_scan2<<<1, 256, 0, stream>>>(bsum);
    k_scan3<<<NB_NODE, 256, 0, stream>>>(cntcur, bsum, rowptr, dinv);
    k_fill <<<NB_EDGE, 256, 0, stream>>>(src, dst, ew, dinv, cntcur, csr);
    k_prep <<<40, 256, 0, stream>>>(W1, wt1, W2, wt2);

    // conv1: t1 = [x|emb] @ W1 (bf16) ; out1 = csr-aggregate + self + b1 (fp32)
    k_gemm<0><<<NB_GEMM, 256, 0, stream>>>(x, emb, node_ids, wt1, tbf, K1);
    k_agg<0, 4><<<(N_NODES + 3) / 4, 256, 0, stream>>>(csr, rowptr, dinv, tbf, b1,
                                                       batch, out1, sums, counts);

    // conv2: t2 = relu(out1) @ W2 (bf16) ; fused aggregate+relu+pool
    k_gemm<1><<<NB_GEMM, 256, 0, stream>>>(out1, nullptr, nullptr, wt2, tbf, HIDDEN);
    k_agg<1, 16><<<(N_NODES + 15) / 16, 1024, 0, stream>>>(csr, rowptr, dinv, tbf, b2,
                                                           batch, nullptr, sums, counts);

    // classifier
    k_final<<<N_GRAPHS, 64, 0, stream>>>(sums, counts, fcW, fcb, out);
}

// Round 7
// 522.795 us; speedup vs baseline: 2.1029x; 1.0502x over previous
//
#include <hip/hip_runtime.h>
#include <hip/hip_bf16.h>

#define N_NODES 50000
#define N_EDGES 500000
#define N_FEAT 128
#define EMB_DIM 1024
#define HIDDEN 128
#define OUT_DIM 10
#define N_GRAPHS 64
#define NB_NODE 196   // ceil(N_NODES/256)

typedef __attribute__((ext_vector_type(8))) short short8;   // 8 bf16 = 4 VGPR (MFMA A/B frag)
typedef __attribute__((ext_vector_type(4))) float f32x4;    // MFMA C/D frag

// ---- fp32 -> bf16 RTN-even (finite inputs) ----
__device__ __forceinline__ unsigned short f2bf(float f) {
    unsigned int u = __float_as_uint(f);
    return (unsigned short)((u + 0x7fffu + ((u >> 16) & 1u)) >> 16);
}
// unpack a dword holding 2 bf16 (elements 2k, 2k+1); pack the inverse
__device__ __forceinline__ float bflo(unsigned int r) { return __uint_as_float(r << 16); }
__device__ __forceinline__ float bfhi(unsigned int r) { return __uint_as_float(r & 0xffff0000u); }
__device__ __forceinline__ unsigned int packbf(float lo, float hi) {
    return ((unsigned int)f2bf(hi) << 16) | f2bf(lo);
}

// ---------------- init: dc=0 (packed deg), zero pool buffers ----------------
__global__ __launch_bounds__(256) void k_init(unsigned long long* __restrict__ dc,
                                              float* __restrict__ sums,
                                              float* __restrict__ counts) {
    int i = blockIdx.x * 256 + threadIdx.x;
    if (i < N_NODES) dc[i] = 0ULL;
    if (i < N_GRAPHS * HIDDEN) sums[i] = 0.0f;
    if (i < N_GRAPHS) counts[i] = 0.0f;
}

// ------- degree scatter: ONE u64 atomic = (count<<32) | fixedpoint(ew, 2^24) --------
// ew in [0,1): fx < 2^24; max in-degree << 128 so low word never carries into count.
__global__ __launch_bounds__(256) void k_deg(const int* __restrict__ dst,
                                             const float* __restrict__ ew,
                                             unsigned long long* __restrict__ dc) {
    int e = blockIdx.x * 256 + threadIdx.x;
    if (e < N_EDGES) {
        unsigned int fx = (unsigned int)(ew[e] * 16777216.0f);
        atomicAdd(&dc[dst[e]], (1ULL << 32) | (unsigned long long)fx);
    }
}

// ---------------- scan pass 1: per-block (256 nodes) reduce of counts ----------------
__global__ __launch_bounds__(256) void k_scan1(const unsigned long long* __restrict__ dc,
                                               int* __restrict__ bsum) {
    __shared__ int wsum[4];
    int i = blockIdx.x * 256 + threadIdx.x;
    int v = (i < N_NODES) ? (int)((const uint2*)dc)[i].y : 0;
#pragma unroll
    for (int off = 32; off; off >>= 1) v += __shfl_down(v, off, 64);
    if ((threadIdx.x & 63) == 0) wsum[threadIdx.x >> 6] = v;
    __syncthreads();
    if (threadIdx.x == 0) bsum[blockIdx.x] = wsum[0] + wsum[1] + wsum[2] + wsum[3];
}

// ---------------- scan pass 2: exclusive scan of NB_NODE block sums (1 block) ------
__global__ __launch_bounds__(256) void k_scan2(int* __restrict__ bsum) {
    __shared__ int sh[256];
    int t = threadIdx.x;
    int v = (t < NB_NODE) ? bsum[t] : 0;
    sh[t] = v;
    __syncthreads();
    for (int off = 1; off < 256; off <<= 1) {
        int add = (t >= off) ? sh[t - off] : 0;
        __syncthreads();
        sh[t] += add;
        __syncthreads();
    }
    if (t < NB_NODE) bsum[t] = sh[t] - v;  // exclusive
}

// -------- scan pass 3: per-block exclusive scan + offset; dinv from packed dc -------
__global__ __launch_bounds__(256) void k_scan3(const unsigned long long* __restrict__ dc,
                                               const int* __restrict__ bofs,
                                               int* __restrict__ cursor,
                                               int* __restrict__ rowptr,
                                               float* __restrict__ dinv) {
    __shared__ int sh[256];
    const int t = threadIdx.x;
    const int i = blockIdx.x * 256 + t;
    uint2 d = (i < N_NODES) ? ((const uint2*)dc)[i] : make_uint2(0u, 0u);
    int v = (int)d.y;
    sh[t] = v;
    __syncthreads();
    for (int off = 1; off < 256; off <<= 1) {
        int add = (t >= off) ? sh[t - off] : 0;
        __syncthreads();
        sh[t] += add;
        __syncthreads();
    }
    int ex = sh[t] - v + bofs[blockIdx.x];
    if (i < N_NODES) {
        rowptr[i] = ex;
        cursor[i] = ex;
        float deg = 1.0f + (float)d.x * (1.0f / 16777216.0f);  // self loop + Σew
        dinv[i] = 1.0f / sqrtf(deg);
    }
    if (i == 0) rowptr[N_NODES] = N_EDGES;
}

// ---------------- fill CSR: csr[pos] = (src, norm) ----------------
__global__ __launch_bounds__(256) void k_fill(const int* __restrict__ src,
                                              const int* __restrict__ dst,
                                              const float* __restrict__ ew,
                                              const float* __restrict__ dinv,
                                              int* __restrict__ cursor,
                                              int2* __restrict__ csr) {
    int e = blockIdx.x * 256 + threadIdx.x;
    if (e >= N_EDGES) return;
    int s = src[e], d = dst[e];
    int pos = atomicAdd(&cursor[d], 1);
    float norm = dinv[s] * ew[e] * dinv[d];
    csr[pos] = make_int2(s, __float_as_int(norm));
}

// ---------------- W (K x 128) -> Wt (128 x K) bf16 (both W1, W2) ----------------
__device__ __forceinline__ void prep_one(const float* __restrict__ W,
                                         unsigned short* __restrict__ Wt,
                                         int K, int t) {
    int n = t & 127;
    int c = t >> 7;
    if (c * 16 >= K) return;
    short8 h0, h1;
#pragma unroll
    for (int i = 0; i < 16; i++) {
        unsigned short h = f2bf(W[(size_t)(c * 16 + i) * HIDDEN + n]);
        if (i < 8) h0[i] = (short)h;
        else       h1[i - 8] = (short)h;
    }
    size_t o = (size_t)n * K + c * 16;
    *(short8*)&Wt[o] = h0;
    *(short8*)&Wt[o + 8] = h1;
}

__global__ __launch_bounds__(256) void k_prep(const float* __restrict__ W1,
                                              unsigned short* __restrict__ Wt1,
                                              const float* __restrict__ W2,
                                              unsigned short* __restrict__ Wt2) {
    int b = blockIdx.x;
    if (b < 36) prep_one(W1, Wt1, N_FEAT + EMB_DIM, b * 256 + threadIdx.x);
    else        prep_one(W2, Wt2, HIDDEN, (b - 36) * 256 + threadIdx.x);
}

// ---------------- bf16 MFMA GEMM: tbf[M,128] = A[M,K] @ W[K,128], bf16 out ----------
// Block: 128x128, 256 threads (4 waves 2x2), 64x64 per wave, BK=32, fp32 accum.
// MODE 0: A row m = [ x[m,0:128] | emb[ids[m],0:1024] ]  (K=1152, fp32 -> bf16)
// MODE 1: A row m = Xb[m,0:128] (already-relu'd bf16, straight copy)  (K=128)
template <int MODE>
__global__ __launch_bounds__(256) void k_gemm(const float* __restrict__ X,
                                              const unsigned short* __restrict__ Xb,
                                              const float* __restrict__ EMB,
                                              const int* __restrict__ ids,
                                              const unsigned short* __restrict__ Wt,
                                              unsigned short* __restrict__ tbf, int K) {
    __shared__ unsigned short As[128][40];  // [row][k], stride 40 (80 B, 16B-aligned)
    __shared__ unsigned short Bs[128][40];  // [col][k]

    const int tid = threadIdx.x;
    const int lane = tid & 63;
    const int wv = tid >> 6;
    const int wm = wv >> 1, wn = wv & 1;     // wave quadrant
    const int fr = lane & 15;                // frag row/col
    const int fq = lane >> 4;                // frag k-octet
    const int mBase = blockIdx.x * 128;

    const int aRow = tid >> 1;
    const int aOff = (tid & 1) * 16;
    const int m = mBase + aRow;
    const int mc = (m < N_NODES) ? m : (N_NODES - 1);
    int embRow = 0;
    if (MODE == 0) embRow = ids[mc];

    f32x4 acc[4][4];
#pragma unroll
    for (int i = 0; i < 4; i++)
#pragma unroll
        for (int j = 0; j < 4; j++) acc[i][j] = (f32x4){0.f, 0.f, 0.f, 0.f};

    // prefetch k0=0 globals
    float av[16];
    short8 axb0, axb1;
    short8 bh0, bh1;
    {
        if (MODE == 0) {
            const float* aptr = X + (size_t)mc * N_FEAT + aOff;
            *(float4*)&av[0]  = *(const float4*)(aptr);
            *(float4*)&av[4]  = *(const float4*)(aptr + 4);
            *(float4*)&av[8]  = *(const float4*)(aptr + 8);
            *(float4*)&av[12] = *(const float4*)(aptr + 12);
        } else {
            const unsigned short* aptr = Xb + (size_t)mc * HIDDEN + aOff;
            axb0 = *(const short8*)(aptr);
            axb1 = *(const short8*)(aptr + 8);
        }
        size_t bo = (size_t)aRow * K + aOff;
        bh0 = *(const short8*)&Wt[bo];
        bh1 = *(const short8*)&Wt[bo + 8];
    }

    for (int k0 = 0; k0 < K; k0 += 32) {
        short8 ah0, ah1;
        if (MODE == 0) {
#pragma unroll
            for (int i = 0; i < 16; i++) {
                unsigned short h = f2bf(av[i]);
                if (i < 8) ah0[i] = (short)h;
                else       ah1[i - 8] = (short)h;
            }
        } else {
            ah0 = axb0; ah1 = axb1;
        }
        *(short8*)&As[aRow][aOff] = ah0; *(short8*)&As[aRow][aOff + 8] = ah1;
        *(short8*)&Bs[aRow][aOff] = bh0; *(short8*)&Bs[aRow][aOff + 8] = bh1;
        __syncthreads();

        // prefetch next k-step globals (hidden behind MFMAs)
        int k1 = k0 + 32;
        if (k1 < K) {
            if (MODE == 0) {
                const float* aptr = (k1 < N_FEAT)
                    ? X + (size_t)mc * N_FEAT + k1 + aOff
                    : EMB + (size_t)embRow * EMB_DIM + (k1 - N_FEAT) + aOff;
                *(float4*)&av[0]  = *(const float4*)(aptr);
                *(float4*)&av[4]  = *(const float4*)(aptr + 4);
                *(float4*)&av[8]  = *(const float4*)(aptr + 8);
                *(float4*)&av[12] = *(const float4*)(aptr + 12);
            } else {
                const unsigned short* aptr = Xb + (size_t)mc * HIDDEN + k1 + aOff;
                axb0 = *(const short8*)(aptr);
                axb1 = *(const short8*)(aptr + 8);
            }
            size_t bo = (size_t)aRow * K + k1 + aOff;
            bh0 = *(const short8*)&Wt[bo];
            bh1 = *(const short8*)&Wt[bo + 8];
        }

        short8 aF[4], bF[4];
#pragma unroll
        for (int i = 0; i < 4; i++) {
            aF[i] = *(const short8*)&As[wm * 64 + i * 16 + fr][fq * 8];
            bF[i] = *(const short8*)&Bs[wn * 64 + i * 16 + fr][fq * 8];
        }

#pragma unroll
        for (int i = 0; i < 4; i++)
#pragma unroll
            for (int j = 0; j < 4; j++)
                acc[i][j] = __builtin_amdgcn_mfma_f32_16x16x32_bf16(aF[i], bF[j], acc[i][j], 0, 0, 0);
        __syncthreads();
    }

    // epilogue: C/D map col=lane&15, row=(lane>>4)*4+reg ; write bf16
#pragma unroll
    for (int i = 0; i < 4; i++) {
#pragma unroll
        for (int j = 0; j < 4; j++) {
            int gcol = wn * 64 + j * 16 + fr;
#pragma unroll
            for (int r = 0; r < 4; r++) {
                int grow = mBase + wm * 64 + i * 16 + fq * 4 + r;
                if (grow < N_NODES) tbf[(size_t)grow * HIDDEN + gcol] = f2bf(acc[i][j][r]);
            }
        }
    }
}

// ---------------- CSR gather-aggregate, wave/node, 16 lanes per edge-row ------------
// 4 edges per wave-step, uint4 (16B) per lane; groups reduced by shfl_xor butterfly.
// acc[n,:] = sum_e norm_e * t[src_e,:] + dinv[n]^2 * t[n,:] + b ; then relu.
// POOL=0: write bf16 row (= h1, feeds gemm1).  POOL=1: per-block LDS pool.
template <int POOL, int NWAVE>
__global__ __launch_bounds__(NWAVE * 64) void k_agg(const int2* __restrict__ csr,
                                                    const int* __restrict__ rowptr,
                                                    const float* __restrict__ dinv,
                                                    const unsigned short* __restrict__ tbf,
                                                    const float* __restrict__ bias,
                                                    const int* __restrict__ batch,
                                                    unsigned short* __restrict__ outb,
                                                    float* __restrict__ sums,
                                                    float* __restrict__ counts) {
    __shared__ float lsum[HIDDEN];
    __shared__ int lcnt;
    const int wv = threadIdx.x >> 6;
    const int lane = threadIdx.x & 63;
    const int grp = lane >> 4;       // edge slot within 4-group
    const int q = lane & 15;         // column quad: cols q*8 .. q*8+7
    const int n = blockIdx.x * NWAVE + wv;
    const uint4* t128 = (const uint4*)tbf;   // row n = 16 uint4 at n*16

    if (POOL) {
        if (threadIdx.x < HIDDEN) lsum[threadIdx.x] = 0.f;
        if (threadIdx.x == 0) lcnt = 0;
        __syncthreads();
    }

    float acc[8] = {};
    if (n < N_NODES) {
        const int beg = rowptr[n];
        const int end = rowptr[n + 1];
        const float di = dinv[n];
        const float wself = (grp == 0) ? di * di : 0.f;
        uint4 sr = t128[(size_t)n * 16 + q];
        acc[0] = wself * bflo(sr.x); acc[1] = wself * bfhi(sr.x);
        acc[2] = wself * bflo(sr.y); acc[3] = wself * bfhi(sr.y);
        acc[4] = wself * bflo(sr.z); acc[5] = wself * bfhi(sr.z);
        acc[6] = wself * bflo(sr.w); acc[7] = wself * bfhi(sr.w);
        if (grp == 0) {
            float4 b0 = ((const float4*)bias)[q * 2];
            float4 b1 = ((const float4*)bias)[q * 2 + 1];
            acc[0] += b0.x; acc[1] += b0.y; acc[2] += b0.z; acc[3] += b0.w;
            acc[4] += b1.x; acc[5] += b1.y; acc[6] += b1.z; acc[7] += b1.w;
        }

        for (int base = beg; base < end; base += 64) {
            int cnt = end - base; if (cnt > 64) cnt = 64;
            int2 ce = (lane < cnt) ? csr[base + lane] : make_int2(0, 0);
            int j = 0;
            for (; j + 8 <= cnt; j += 8) {       // 8 edges: 2 uint4 gathers in flight
                int   sA = __shfl(ce.x, j + grp);
                float wA = __int_as_float(__shfl(ce.y, j + grp));
                int   sB = __shfl(ce.x, j + 4 + grp);
                float wB = __int_as_float(__shfl(ce.y, j + 4 + grp));
                uint4 rA = t128[(size_t)sA * 16 + q];
                uint4 rB = t128[(size_t)sB * 16 + q];
                acc[0] = fmaf(wA, bflo(rA.x), acc[0]); acc[1] = fmaf(wA, bfhi(rA.x), acc[1]);
                acc[2] = fmaf(wA, bflo(rA.y), acc[2]); acc[3] = fmaf(wA, bfhi(rA.y), acc[3]);
                acc[4] = fmaf(wA, bflo(rA.z), acc[4]); acc[5] = fmaf(wA, bfhi(rA.z), acc[5]);
                acc[6] = fmaf(wA, bflo(rA.w), acc[6]); acc[7] = fmaf(wA, bfhi(rA.w), acc[7]);
                acc[0] = fmaf(wB, bflo(rB.x), acc[0]); acc[1] = fmaf(wB, bfhi(rB.x), acc[1]);
                acc[2] = fmaf(wB, bflo(rB.y), acc[2]); acc[3] = fmaf(wB, bfhi(rB.y), acc[3]);
                acc[4] = fmaf(wB, bflo(rB.z), acc[4]); acc[5] = fmaf(wB, bfhi(rB.z), acc[5]);
                acc[6] = fmaf(wB, bflo(rB.w), acc[6]); acc[7] = fmaf(wB, bfhi(rB.w), acc[7]);
            }
            for (; j < cnt; j += 4) {            // tail groups (w=0 pads beyond cnt)
                int   s = __shfl(ce.x, j + grp);
                float w = __int_as_float(__shfl(ce.y, j + grp));
                uint4 r = t128[(size_t)s * 16 + q];
                acc[0] = fmaf(w, bflo(r.x), acc[0]); acc[1] = fmaf(w, bfhi(r.x), acc[1]);
                acc[2] = fmaf(w, bflo(r.y), acc[2]); acc[3] = fmaf(w, bfhi(r.y), acc[3]);
                acc[4] = fmaf(w, bflo(r.z), acc[4]); acc[5] = fmaf(w, bfhi(r.z), acc[5]);
                acc[6] = fmaf(w, bflo(r.w), acc[6]); acc[7] = fmaf(w, bfhi(r.w), acc[7]);
            }
        }
    }

    // reduce the 4 edge-groups: lanes l, l^16, l^32, l^48 hold same columns
#pragma unroll
    for (int i = 0; i < 8; i++) {
        acc[i] += __shfl_xor(acc[i], 16);
        acc[i] += __shfl_xor(acc[i], 32);
    }

    if (!POOL) {
        if (n < N_NODES && grp == 0) {
#pragma unroll
            for (int i = 0; i < 8; i++) acc[i] = fmaxf(acc[i], 0.f);  // relu (h1)
            uint4 o;
            o.x = packbf(acc[0], acc[1]);
            o.y = packbf(acc[2], acc[3]);
            o.z = packbf(acc[4], acc[5]);
            o.w = packbf(acc[6], acc[7]);
            ((uint4*)outb)[(size_t)n * 16 + q] = o;
        }
    } else {
        if (n < N_NODES && grp == 0) {
#pragma unroll
            for (int i = 0; i < 8; i++) acc[i] = fmaxf(acc[i], 0.f);  // relu
            int g = batch[n];
            int g0 = batch[blockIdx.x * NWAVE];
            if (g == g0) {
#pragma unroll
                for (int i = 0; i < 8; i++) atomicAdd(&lsum[q * 8 + i], acc[i]);
                if (lane == 0) atomicAdd(&lcnt, 1);
            } else {  // rare boundary node: direct global
#pragma unroll
                for (int i = 0; i < 8; i++) atomicAdd(&sums[g * HIDDEN + q * 8 + i], acc[i]);
                if (lane == 0) atomicAdd(&counts[g], 1.0f);
            }
        }
        __syncthreads();
        int g0 = batch[blockIdx.x * NWAVE];
        if (threadIdx.x < HIDDEN) atomicAdd(&sums[g0 * HIDDEN + threadIdx.x], lsum[threadIdx.x]);
        if (threadIdx.x == 0) atomicAdd(&counts[g0], (float)lcnt);
    }
}

// ---------------- final: out[g,o] = (sums[g,:]/max(cnt,1)) @ fcW + fcb -------------
__global__ __launch_bounds__(64) void k_final(const float* __restrict__ sums,
                                              const float* __restrict__ counts,
                                              const float* __restrict__ fcW,
                                              const float* __restrict__ fcb,
                                              float* __restrict__ out) {
    int g = blockIdx.x;
    int o = threadIdx.x;
    if (o >= OUT_DIM) return;
    float inv = 1.0f / fmaxf(counts[g], 1.0f);
    float acc = 0.f;
    for (int f = 0; f < HIDDEN; f++)
        acc = fmaf(sums[g * HIDDEN + f], fcW[f * OUT_DIM + o], acc);
    out[g * OUT_DIM + o] = acc * inv + fcb[o];
}

extern "C" void kernel_launch(void* const* d_in, const int* in_sizes, int n_in,
                              void* d_out, int out_size, void* d_ws, size_t ws_size,
                              hipStream_t stream) {
    const float* x      = (const float*)d_in[0];
    const float* ew     = (const float*)d_in[1];
    const float* emb    = (const float*)d_in[2];
    const float* W1     = (const float*)d_in[3];
    const float* b1     = (const float*)d_in[4];
    const float* W2     = (const float*)d_in[5];
    const float* b2     = (const float*)d_in[6];
    const float* fcW    = (const float*)d_in[7];
    const float* fcb    = (const float*)d_in[8];
    const int* edge_idx = (const int*)d_in[9];
    const int* batch    = (const int*)d_in[10];
    const int* node_ids = (const int*)d_in[11];
    float* out = (float*)d_out;

    const int* src = edge_idx;             // edge_index[0]
    const int* dst = edge_idx + N_EDGES;   // edge_index[1]

    // workspace layout (float units; bf16 buffers 16B-aligned)
    float* ws     = (float*)d_ws;
    float* dinv   = ws;                                        // 50048
    unsigned long long* dc = (unsigned long long*)(ws + 50048);// 50000 u64 = 100000 f
    int*   cursor = (int*)(ws + 150048);                       // 50048
    int*   rowptr = (int*)(ws + 200096);                       // 50056
    int*   bsum   = (int*)(ws + 250152);                       // 256
    int2*  csr    = (int2*)(ws + 250408);                      // 500000 int2 = 1M f
    unsigned short* tbf   = (unsigned short*)(ws + 1250408);   // 6.4M bf16 = 3.2M f
    unsigned short* out1b = (unsigned short*)(ws + 4450408);   // 6.4M bf16 (h1)
    float* sums   = ws + 7650408;                              // 8192
    float* counts = sums + N_GRAPHS * HIDDEN;                  // 64
    unsigned short* wt1 = (unsigned short*)(ws + 7658664);     // 147456 bf16
    unsigned short* wt2 = (unsigned short*)(ws + 7732392);     // 16384 bf16
    // end ~7740584 floats = 31 MB

    const int NB_EDGE = (N_EDGES + 255) / 256;           // 1954
    const int NB_GEMM = (N_NODES + 127) / 128;           // 391
    const int K1 = N_FEAT + EMB_DIM;                     // 1152

    // preprocessing: packed degrees, multi-block scan, CSR, weights
    k_init <<<NB_NODE, 256, 0, stream>>>(dc, sums, counts);
    k_deg  <<<NB_EDGE, 256, 0, stream>>>(dst, ew, dc);
    k_scan1<<<NB_NODE, 256, 0, stream>>>(dc, bsum);
    k_scan2<<<1, 256, 0, stream>>>(bsum);
    k_scan3<<<NB_NODE, 256, 0, stream>>>(dc, bsum, cursor, rowptr, dinv);
    k_fill <<<NB_EDGE, 256, 0, stream>>>(src, dst, ew, dinv, cursor, csr);
    k_prep <<<40, 256, 0, stream>>>(W1, wt1, W2, wt2);

    // conv1: t1 = [x|emb] @ W1 (bf16) ; h1 = relu(aggregate + self + b1) (bf16)
    k_gemm<0><<<NB_GEMM, 256, 0, stream>>>(x, nullptr, emb, node_ids, wt1, tbf, K1);
    k_agg<0, 4><<<(N_NODES + 3) / 4, 256, 0, stream>>>(csr, rowptr, dinv, tbf, b1,
                                                       batch, out1b, sums, counts);

    // conv2: t2 = h1 @ W2 (bf16) ; fused aggregate+relu+pool
    k_gemm<1><<<NB_GEMM, 256, 0, stream>>>(nullptr, out1b, nullptr, nullptr, wt2, tbf, HIDDEN);
    k_agg<1, 16><<<(N_NODES + 15) / 16, 1024, 0, stream>>>(csr, rowptr, dinv, tbf, b2,
                                                           batch, nullptr, sums, counts);

    // classifier
    k_final<<<N_GRAPHS, 64, 0, stream>>>(sums, counts, fcW, fcb, out);
}